// Round 10
// baseline (335.666 us; speedup 1.0000x reference)
//
#include <hip/hip_runtime.h>
#include <math.h>

static constexpr int Tt = 32;
static constexpr int Nn = 1024;
static constexpr int KN = 16;   // K + self

typedef float v2f __attribute__((ext_vector_type(2)));

// ---------------------------------------------------------------------------
// Cross-lane primitives: DPP for xor1/xor2 (pure VALU), ds_swizzle otherwise.
// ---------------------------------------------------------------------------
template <int M>
__device__ __forceinline__ float lane_xor(float v) {
    if constexpr (M == 1)
        return __int_as_float(__builtin_amdgcn_mov_dpp(__float_as_int(v), 0xB1, 0xF, 0xF, true));
    else if constexpr (M == 2)
        return __int_as_float(__builtin_amdgcn_mov_dpp(__float_as_int(v), 0x4E, 0xF, 0xF, true));
    else
        return __shfl_xor(v, M);
}
template <int M>
__device__ __forceinline__ v2f lane_xor2(v2f v) {
    v2f r; r.x = lane_xor<M>(v.x); r.y = lane_xor<M>(v.y); return r;
}
__device__ __forceinline__ float bcastlane(float v, int l) {
    return __int_as_float(__builtin_amdgcn_readlane(__float_as_int(v), l));
}
__device__ __forceinline__ constexpr int rev4(int k) {
    return ((k & 1) << 3) | ((k & 2) << 1) | ((k & 4) >> 1) | ((k & 8) >> 3);
}
__device__ __forceinline__ v2f max2(v2f a, v2f b) { return __builtin_elementwise_max(a, b); }
__device__ __forceinline__ v2f fma2(v2f a, v2f b, v2f c) { return __builtin_elementwise_fma(a, b, c); }

// fold NV v2f values into NV/2, routing by lane bit M
template <int NV, int M>
__device__ __forceinline__ void fstage2(v2f* p, int lane) {
#pragma unroll
    for (int k2 = 0; k2 < NV / 2; ++k2) {
        v2f a_ = p[k2], b_ = p[k2 + NV / 2];
        v2f t_, o_;
        t_.x = (lane & M) ? a_.x : b_.x; t_.y = (lane & M) ? a_.y : b_.y;
        o_.x = (lane & M) ? b_.x : a_.x; o_.y = (lane & M) ? b_.y : a_.y;
        p[k2] = o_ + lane_xor2<M>(t_);
    }
}
__device__ __forceinline__ v2f fold16_2(v2f* p, int lane) {
    fstage2<16, 1>(p, lane); fstage2<8, 2>(p, lane);
    fstage2<4, 4>(p, lane);  fstage2<2, 8>(p, lane);
    return p[0];
}
__device__ __forceinline__ v2f rmax16_2(v2f x) {
    x = max2(x, lane_xor2<1>(x)); x = max2(x, lane_xor2<2>(x));
    x = max2(x, lane_xor2<4>(x)); x = max2(x, lane_xor2<8>(x));
    return x;
}
__device__ __forceinline__ v2f rsum16_2(v2f x) {
    x += lane_xor2<1>(x); x += lane_xor2<2>(x);
    x += lane_xor2<4>(x); x += lane_xor2<8>(x);
    return x;
}

// ---------------------------------------------------------------------------
// 1. Recover source indices (order-free), layout srcs[t][n][16].
//    1024 blocks (4/CU) x 256 thr; 32-target stripes; 16-deep int4 batches
//    so HBM latency is covered (BW-bound, not latency-bound).
// ---------------------------------------------------------------------------
__global__ __launch_bounds__(256) void k_srcs(const int* __restrict__ edge,
                                              int* __restrict__ srcs)
{
    __shared__ int cnt[32];
    const int t    = blockIdx.x >> 5;          // 0..31
    const int tgt0 = (blockIdx.x & 31) << 5;   // 0,32,...,992
    const int x = threadIdx.x & 7;             // int4 group -> 4 targets
    const int y = threadIdx.x >> 3;            // s-group 0..31
    if (threadIdx.x < 32) cnt[threadIdx.x] = 0;
    __syncthreads();

    const int c0 = 4 * x;
    const int s0 = y * 32;
    const int* e = edge + (size_t)t * Nn * Nn + tgt0 + c0;

#pragma unroll
    for (int i0 = 0; i0 < 32; i0 += 16) {
        int4 v[16];
#pragma unroll
        for (int j = 0; j < 16; ++j)
            v[j] = *reinterpret_cast<const int4*>(e + (size_t)(s0 + i0 + j) * Nn);
#pragma unroll
        for (int j = 0; j < 16; ++j) {
            const int s = s0 + i0 + j;
            if (v[j].x) { int sl = atomicAdd(&cnt[c0],     1); if (sl < KN - 1) srcs[((size_t)t * Nn + tgt0 + c0)     * KN + sl] = s; }
            if (v[j].y) { int sl = atomicAdd(&cnt[c0 + 1], 1); if (sl < KN - 1) srcs[((size_t)t * Nn + tgt0 + c0 + 1) * KN + sl] = s; }
            if (v[j].z) { int sl = atomicAdd(&cnt[c0 + 2], 1); if (sl < KN - 1) srcs[((size_t)t * Nn + tgt0 + c0 + 2) * KN + sl] = s; }
            if (v[j].w) { int sl = atomicAdd(&cnt[c0 + 3], 1); if (sl < KN - 1) srcs[((size_t)t * Nn + tgt0 + c0 + 3) * KN + sl] = s; }
        }
    }
    if (threadIdx.x < 32)
        srcs[((size_t)t * Nn + tgt0 + threadIdx.x) * KN + (KN - 1)] = tgt0 + threadIdx.x;
}

// ---------------------------------------------------------------------------
// 2. Register-blocked dual linear, HEAD-INTERLEAVED float2 output (c, c+HC).
// ---------------------------------------------------------------------------
template <int FI, int FO>
__global__ __launch_bounds__(256) void k_lin2t(
    const float* __restrict__ X,
    const float* __restrict__ Wl, const float* __restrict__ bl,
    const float* __restrict__ Wr, const float* __restrict__ br,
    float* __restrict__ Yl, float* __restrict__ Yr, int rows)
{
    constexpr int HC = FO / 2;
    constexpr int RG = 256 / HC;
    constexpr int R  = 8;
    constexpr int BR = RG * R;
    constexpr int F4 = FI / 4;
    __shared__ float xs[BR][FI];

    const int tid  = threadIdx.x;
    const int c    = tid % HC;
    const int g    = tid / HC;
    const int row0 = blockIdx.x * BR;

#pragma unroll
    for (int idx = tid; idx < BR * F4; idx += 256) {
        int r = idx / F4, q = idx % F4;
        reinterpret_cast<float4*>(&xs[r][0])[q] =
            reinterpret_cast<const float4*>(X + (size_t)(row0 + r) * FI)[q];
    }
    __syncthreads();

    float al0[R], al1[R], ar0[R], ar1[R];
    const float bl0 = bl[c], bl1 = bl[c + HC], br0 = br[c], br1 = br[c + HC];
#pragma unroll
    for (int r = 0; r < R; ++r) { al0[r] = bl0; al1[r] = bl1; ar0[r] = br0; ar1[r] = br1; }

    const int rb = g * R;
#pragma unroll
    for (int i0 = 0; i0 < FI; i0 += 4) {
        float4 xv[R];
#pragma unroll
        for (int r = 0; r < R; ++r)
            xv[r] = *reinterpret_cast<const float4*>(&xs[rb + r][i0]);
#pragma unroll
        for (int j = 0; j < 4; ++j) {
            const float wl0 = Wl[(i0 + j) * FO + c];
            const float wl1 = Wl[(i0 + j) * FO + c + HC];
            const float wr0 = Wr[(i0 + j) * FO + c];
            const float wr1 = Wr[(i0 + j) * FO + c + HC];
#pragma unroll
            for (int r = 0; r < R; ++r) {
                const float xx = (&xv[r].x)[j];
                al0[r] = fmaf(xx, wl0, al0[r]);
                al1[r] = fmaf(xx, wl1, al1[r]);
                ar0[r] = fmaf(xx, wr0, ar0[r]);
                ar1[r] = fmaf(xx, wr1, ar1[r]);
            }
        }
    }
#pragma unroll
    for (int r = 0; r < R; ++r) {
        const size_t ro = (size_t)(row0 + rb + r) * FO;
        reinterpret_cast<float2*>(Yl + ro)[c] = make_float2(al0[r], al1[r]);
        reinterpret_cast<float2*>(Yr + ro)[c] = make_float2(ar0[r], ar1[r]);
    }
}

// ---------------------------------------------------------------------------
// 2d. Quad linear for r1+f1: E read once, 4 interleaved outputs.
// ---------------------------------------------------------------------------
__global__ __launch_bounds__(256) void k_lin4t(
    const float* __restrict__ E,
    const float* __restrict__ Wlr, const float* __restrict__ blr,
    const float* __restrict__ Wrr, const float* __restrict__ brr,
    const float* __restrict__ Wlf, const float* __restrict__ blf,
    const float* __restrict__ Wrf, const float* __restrict__ brf,
    float* __restrict__ Yrl, float* __restrict__ Yrr,
    float* __restrict__ Yfl, float* __restrict__ Yfr)
{
    constexpr int FI = 32, FO = 128, HC = 64, R = 4, BR = 16, F4 = FI / 4;
    __shared__ float xs[BR][FI];

    const int tid  = threadIdx.x;
    const int c    = tid % HC;
    const int g    = tid / HC;
    const int row0 = blockIdx.x * BR;

#pragma unroll
    for (int idx = tid; idx < BR * F4; idx += 256) {
        int r = idx / F4, q = idx % F4;
        reinterpret_cast<float4*>(&xs[r][0])[q] =
            reinterpret_cast<const float4*>(E + (size_t)(row0 + r) * FI)[q];
    }
    __syncthreads();

    float rl0[R], rl1[R], rr0[R], rr1[R], fl0[R], fl1[R], fr0[R], fr1[R];
    const float brl0 = blr[c], brl1 = blr[c + HC], brr0 = brr[c], brr1 = brr[c + HC];
    const float bfl0 = blf[c], bfl1 = blf[c + HC], bfr0 = brf[c], bfr1 = brf[c + HC];
#pragma unroll
    for (int r = 0; r < R; ++r) {
        rl0[r] = brl0; rl1[r] = brl1; rr0[r] = brr0; rr1[r] = brr1;
        fl0[r] = bfl0; fl1[r] = bfl1; fr0[r] = bfr0; fr1[r] = bfr1;
    }

    const int rb = g * R;
#pragma unroll
    for (int i0 = 0; i0 < FI; i0 += 4) {
        float4 xv[R];
#pragma unroll
        for (int r = 0; r < R; ++r)
            xv[r] = *reinterpret_cast<const float4*>(&xs[rb + r][i0]);
#pragma unroll
        for (int j = 0; j < 4; ++j) {
            const int wi = (i0 + j) * FO;
            const float wrl0 = Wlr[wi + c], wrl1 = Wlr[wi + c + HC];
            const float wrr0 = Wrr[wi + c], wrr1 = Wrr[wi + c + HC];
            const float wfl0 = Wlf[wi + c], wfl1 = Wlf[wi + c + HC];
            const float wfr0 = Wrf[wi + c], wfr1 = Wrf[wi + c + HC];
#pragma unroll
            for (int r = 0; r < R; ++r) {
                const float xx = (&xv[r].x)[j];
                rl0[r] = fmaf(xx, wrl0, rl0[r]); rl1[r] = fmaf(xx, wrl1, rl1[r]);
                rr0[r] = fmaf(xx, wrr0, rr0[r]); rr1[r] = fmaf(xx, wrr1, rr1[r]);
                fl0[r] = fmaf(xx, wfl0, fl0[r]); fl1[r] = fmaf(xx, wfl1, fl1[r]);
                fr0[r] = fmaf(xx, wfr0, fr0[r]); fr1[r] = fmaf(xx, wfr1, fr1[r]);
            }
        }
    }
#pragma unroll
    for (int r = 0; r < R; ++r) {
        const int erow = row0 + rb + r;
        if (erow >= Nn) {
            const size_t ro = (size_t)(erow - Nn) * FO;
            reinterpret_cast<float2*>(Yrl + ro)[c] = make_float2(rl0[r], rl1[r]);
            reinterpret_cast<float2*>(Yrr + ro)[c] = make_float2(rr0[r], rr1[r]);
        }
        if (erow < (Tt - 1) * Nn) {
            const size_t ro = (size_t)erow * FO;
            reinterpret_cast<float2*>(Yfl + ro)[c] = make_float2(fl0[r], fl1[r]);
            reinterpret_cast<float2*>(Yfr + ro)[c] = make_float2(fr0[r], fr1[r]);
        }
    }
}

// ---------------------------------------------------------------------------
// 2b. Single linear to 96 cols (GRU layer-0 input gates): Y = X@W^T + b.
// ---------------------------------------------------------------------------
__global__ __launch_bounds__(192) void k_lin96(
    const float* __restrict__ X, const float* __restrict__ W,
    const float* __restrict__ b, float* __restrict__ Y)
{
    __shared__ float wT[32 * 97];
    __shared__ float xs[16][32];

    const int tid = threadIdx.y * 96 + threadIdx.x;
    const int row0 = blockIdx.x * 16;

    for (int idx = tid; idx < 3072; idx += 192) {
        int c = idx >> 5, i = idx & 31;
        wT[i * 97 + c] = W[idx];
    }
    for (int idx = tid; idx < 128; idx += 192)
        reinterpret_cast<float4*>(xs)[idx] =
            reinterpret_cast<const float4*>(X + (size_t)row0 * 32)[idx];
    __syncthreads();

    const int c  = threadIdx.x;
    const int rb = threadIdx.y * 8;
    float acc[8];
    const float bc = b[c];
#pragma unroll
    for (int r = 0; r < 8; ++r) acc[r] = bc;

#pragma unroll
    for (int i = 0; i < 32; ++i) {
        const float w = wT[i * 97 + c];
#pragma unroll
        for (int r = 0; r < 8; ++r)
            acc[r] = fmaf(xs[rb + r][i], w, acc[r]);
    }
#pragma unroll
    for (int r = 0; r < 8; ++r)
        Y[(size_t)(row0 + rb + r) * 96 + c] = acc[r];
}

// ---------------------------------------------------------------------------
// 2c. Fused 2-layer serial GRU.
// ---------------------------------------------------------------------------
__global__ __launch_bounds__(64) void k_gru21(
    const float* __restrict__ gi,
    const float* __restrict__ Whh0, const float* __restrict__ bhh0,
    const float* __restrict__ Wih1, const float* __restrict__ bih1,
    const float* __restrict__ Whh1, const float* __restrict__ bhh1,
    float* __restrict__ E)
{
    const int d    = threadIdx.x & 31;
    const int node = blockIdx.x * 2 + (threadIdx.x >> 5);

    float w0r[32], w0z[32], w0n[32];
    float u1r[32], u1z[32], u1n[32];
    float w1r[32], w1z[32], w1n[32];
#pragma unroll
    for (int q = 0; q < 8; ++q) {
        *reinterpret_cast<float4*>(&w0r[q * 4]) = reinterpret_cast<const float4*>(Whh0 + (size_t)d * 32)[q];
        *reinterpret_cast<float4*>(&w0z[q * 4]) = reinterpret_cast<const float4*>(Whh0 + (size_t)(32 + d) * 32)[q];
        *reinterpret_cast<float4*>(&w0n[q * 4]) = reinterpret_cast<const float4*>(Whh0 + (size_t)(64 + d) * 32)[q];
        *reinterpret_cast<float4*>(&u1r[q * 4]) = reinterpret_cast<const float4*>(Wih1 + (size_t)d * 32)[q];
        *reinterpret_cast<float4*>(&u1z[q * 4]) = reinterpret_cast<const float4*>(Wih1 + (size_t)(32 + d) * 32)[q];
        *reinterpret_cast<float4*>(&u1n[q * 4]) = reinterpret_cast<const float4*>(Wih1 + (size_t)(64 + d) * 32)[q];
        *reinterpret_cast<float4*>(&w1r[q * 4]) = reinterpret_cast<const float4*>(Whh1 + (size_t)d * 32)[q];
        *reinterpret_cast<float4*>(&w1z[q * 4]) = reinterpret_cast<const float4*>(Whh1 + (size_t)(32 + d) * 32)[q];
        *reinterpret_cast<float4*>(&w1n[q * 4]) = reinterpret_cast<const float4*>(Whh1 + (size_t)(64 + d) * 32)[q];
    }
    const float b0r = bhh0[d], b0z = bhh0[32 + d], b0n = bhh0[64 + d];
    const float c1r = bih1[d], c1z = bih1[32 + d], c1n = bih1[64 + d];
    const float b1r = bhh1[d], b1z = bhh1[32 + d], b1n = bhh1[64 + d];

    size_t base = (size_t)node * 96 + d;
    float gr = gi[base], gz = gi[base + 32], gn = gi[base + 64];

    float h0 = 0.0f, h1 = 0.0f;
    for (int t = 0; t < Tt; ++t) {
        float grn = 0.f, gzn = 0.f, gnn = 0.f;
        if (t < Tt - 1) {
            const size_t nb = ((size_t)(t + 1) * Nn + node) * 96 + d;
            grn = gi[nb]; gzn = gi[nb + 32]; gnn = gi[nb + 64];
        }
        float ar = b0r, az = b0z, an = b0n;
#pragma unroll
        for (int i = 0; i < 32; ++i) {
            const float hv = __shfl(h0, i, 32);
            ar = fmaf(w0r[i], hv, ar);
            az = fmaf(w0z[i], hv, az);
            an = fmaf(w0n[i], hv, an);
        }
        float r = __builtin_amdgcn_rcpf(1.0f + expf(-(gr + ar)));
        float z = __builtin_amdgcn_rcpf(1.0f + expf(-(gz + az)));
        float nn2 = tanhf(gn + r * an);
        h0 = (1.0f - z) * nn2 + z * h0;

        float xr = c1r, xz = c1z, xn = c1n;
        ar = b1r; az = b1z; an = b1n;
#pragma unroll
        for (int i = 0; i < 32; ++i) {
            const float xv = __shfl(h0, i, 32);
            const float hv = __shfl(h1, i, 32);
            xr = fmaf(u1r[i], xv, xr);
            xz = fmaf(u1z[i], xv, xz);
            xn = fmaf(u1n[i], xv, xn);
            ar = fmaf(w1r[i], hv, ar);
            az = fmaf(w1z[i], hv, az);
            an = fmaf(w1n[i], hv, an);
        }
        r = __builtin_amdgcn_rcpf(1.0f + expf(-(xr + ar)));
        z = __builtin_amdgcn_rcpf(1.0f + expf(-(xz + az)));
        nn2 = tanhf(xn + r * an);
        h1 = (1.0f - z) * nn2 + z * h1;
        E[((size_t)t * Nn + node) * 32 + d] = h1;
        gr = grn; gz = gzn; gn = gnn;
    }
}

// ---------------------------------------------------------------------------
// 3. GATv2 C=64 (fold structure, v2f-packed math): dense float2 gather, DPP
//    fold, readlane alpha broadcast, optional fused MLP head.
// ---------------------------------------------------------------------------
template <bool HEAD>
__global__ __launch_bounds__(256) void k_gat64(
    const float* __restrict__ gl, const float* __restrict__ gr,
    const int* __restrict__ srcs, const float* __restrict__ att,
    const float* __restrict__ bias, float* __restrict__ out, int rows,
    const float* __restrict__ W2, const float* __restrict__ b2,
    const float* __restrict__ W3, const float* __restrict__ b3)
{
    __shared__ float hb[4][64];
    const int lane = threadIdx.x & 63;
    const int w = threadIdx.x >> 6;
    const int gridB = rows >> 2;
    const int chunk = gridB >> 3;
    const int bid = blockIdx.x;
    const int lb = (bid & 7) * chunk + (bid >> 3);
    const int wave = lb * 4 + w;
    const int t = wave >> 10;
    const int n = wave & (Nn - 1);

    const v2f grl = reinterpret_cast<const v2f*>(gr + (size_t)wave * 128)[lane];
    const v2f a01 = {att[lane], att[64 + lane]};

    const int4* sp = reinterpret_cast<const int4*>(srcs + ((size_t)t * Nn + n) * KN);
    const int4 sA = sp[0], sB = sp[1], sC = sp[2], sD = sp[3];
    int s[KN] = {sA.x, sA.y, sA.z, sA.w, sB.x, sB.y, sB.z, sB.w,
                 sC.x, sC.y, sC.z, sC.w, sD.x, sD.y, sD.z, sD.w};

    v2f g2[KN], p[KN];
#pragma unroll
    for (int k = 0; k < KN; ++k) {
        g2[k] = reinterpret_cast<const v2f*>(gl + ((size_t)t * Nn + s[k]) * 128)[lane];
        v2f e = g2[k] + grl;
        e = max2(e, 0.2f * e);
        p[k] = e * a01;
    }
    v2f lo = fold16_2(p, lane);
    lo += lane_xor2<16>(lo);
    { v2f o; o.x = __shfl_xor(lo.x, 32); o.y = __shfl_xor(lo.y, 32); lo += o; }

    const v2f m = rmax16_2(lo);
    const v2f ex = {expf(lo.x - m.x), expf(lo.y - m.y)};
    const v2f sm = rsum16_2(ex);
    const v2f A = {ex.x * __builtin_amdgcn_rcpf(sm.x), ex.y * __builtin_amdgcn_rcpf(sm.y)};

    v2f acc = {0.0f, 0.0f};
#pragma unroll
    for (int k = 0; k < KN; ++k) {
        const v2f Ab = {bcastlane(A.x, rev4(k)), bcastlane(A.y, rev4(k))};
        acc = fma2(Ab, g2[k], acc);
    }
    float res = 0.5f * (acc.x + acc.y) + bias[lane];
    res = res > 0.0f ? res : expm1f(res);

    if (!HEAD) {
        out[(size_t)wave * 64 + lane] = res;
    } else {
        hb[w][lane] = res;
        __builtin_amdgcn_s_waitcnt(0);
        v2f acc2 = {b2[lane], 0.0f};
#pragma unroll
        for (int i4 = 0; i4 < 16; ++i4) {
            const float4 hv = reinterpret_cast<const float4*>(&hb[w][0])[i4];
            const v2f h01 = {hv.x, hv.y}, h23 = {hv.z, hv.w};
            const v2f wA = {W2[(i4 * 4 + 0) * 64 + lane], W2[(i4 * 4 + 1) * 64 + lane]};
            const v2f wB = {W2[(i4 * 4 + 2) * 64 + lane], W2[(i4 * 4 + 3) * 64 + lane]};
            acc2 = fma2(h01, wA, acc2);
            acc2 = fma2(h23, wB, acc2);
        }
        const float th = tanhf(acc2.x + acc2.y);
        __builtin_amdgcn_s_waitcnt(0);
        hb[w][lane] = th;
        __builtin_amdgcn_s_waitcnt(0);
        if (lane < 50) {
            v2f a2 = {b3[lane], 0.0f};
#pragma unroll
            for (int j4 = 0; j4 < 16; ++j4) {
                const float4 hv = reinterpret_cast<const float4*>(&hb[w][0])[j4];
                const v2f h01 = {hv.x, hv.y}, h23 = {hv.z, hv.w};
                const v2f wA = {W3[(j4 * 4 + 0) * 50 + lane], W3[(j4 * 4 + 1) * 50 + lane]};
                const v2f wB = {W3[(j4 * 4 + 2) * 50 + lane], W3[(j4 * 4 + 3) * 50 + lane]};
                a2 = fma2(h01, wA, a2);
                a2 = fma2(h23, wB, a2);
            }
            out[(size_t)wave * 50 + lane] = a2.x + a2.y;
        }
    }
}

// ---------------------------------------------------------------------------
// 3b. GATv2 C=32: two targets per wave, fold within halves, v2f-packed.
// ---------------------------------------------------------------------------
__global__ __launch_bounds__(256) void k_gat32(
    const float* __restrict__ gl, const float* __restrict__ gr,
    const int* __restrict__ srcs, const float* __restrict__ att,
    const float* __restrict__ bias, float* __restrict__ out, int waves)
{
    const int lane = threadIdx.x & 63;
    const int w = threadIdx.x >> 6;
    const int gridB = waves >> 2;
    const int chunk = gridB >> 3;
    const int bid = blockIdx.x;
    const int lb = (bid & 7) * chunk + (bid >> 3);
    const int wv = lb * 4 + w;
    const int tgt = 2 * wv + (lane >> 5);
    const int t = tgt >> 10;
    const int n = tgt & (Nn - 1);
    const int c = lane & 31;

    const v2f grl = reinterpret_cast<const v2f*>(gr + (size_t)tgt * 64)[c];
    const v2f a01 = {att[c], att[32 + c]};

    const int4* sp = reinterpret_cast<const int4*>(srcs + ((size_t)t * Nn + n) * KN);
    const int4 sA = sp[0], sB = sp[1], sC = sp[2], sD = sp[3];
    int s[KN] = {sA.x, sA.y, sA.z, sA.w, sB.x, sB.y, sB.z, sB.w,
                 sC.x, sC.y, sC.z, sC.w, sD.x, sD.y, sD.z, sD.w};

    v2f g2[KN], p[KN];
#pragma unroll
    for (int k = 0; k < KN; ++k) {
        g2[k] = reinterpret_cast<const v2f*>(gl + ((size_t)t * Nn + s[k]) * 64)[c];
        v2f e = g2[k] + grl;
        e = max2(e, 0.2f * e);
        p[k] = e * a01;
    }
    v2f lo = fold16_2(p, lane);
    lo += lane_xor2<16>(lo);

    const v2f m = rmax16_2(lo);
    const v2f ex = {expf(lo.x - m.x), expf(lo.y - m.y)};
    const v2f sm = rsum16_2(ex);
    const v2f A = {ex.x * __builtin_amdgcn_rcpf(sm.x), ex.y * __builtin_amdgcn_rcpf(sm.y)};

    v2f Ao; Ao.x = __shfl_xor(A.x, 32); Ao.y = __shfl_xor(A.y, 32);
    const bool loHalf = (lane < 32);

    v2f acc = {0.0f, 0.0f};
#pragma unroll
    for (int k = 0; k < KN; ++k) {
        v2f Aa = {bcastlane(A.x, rev4(k)), bcastlane(A.y, rev4(k))};
        v2f Ab = {bcastlane(Ao.x, rev4(k)), bcastlane(Ao.y, rev4(k))};
        v2f Ak; Ak.x = loHalf ? Aa.x : Ab.x; Ak.y = loHalf ? Aa.y : Ab.y;
        acc = fma2(Ak, g2[k], acc);
    }
    float res = 0.5f * (acc.x + acc.y) + bias[c];
    res = res > 0.0f ? res : expm1f(res);
    out[(size_t)tgt * 32 + c] = res;
}

// ---------------------------------------------------------------------------
extern "C" void kernel_launch(void* const* d_in, const int* in_sizes, int n_in,
                              void* d_out, int out_size, void* d_ws, size_t ws_size,
                              hipStream_t stream)
{
    const float* x    = (const float*)d_in[0];
    const int*   edge = (const int*)d_in[1];

    const float *g1_Wl = (const float*)d_in[2],  *g1_bl = (const float*)d_in[3];
    const float *g1_Wr = (const float*)d_in[4],  *g1_br = (const float*)d_in[5];
    const float *g1_att= (const float*)d_in[6],  *g1_b  = (const float*)d_in[7];
    const float *g2_Wl = (const float*)d_in[8],  *g2_bl = (const float*)d_in[9];
    const float *g2_Wr = (const float*)d_in[10], *g2_br = (const float*)d_in[11];
    const float *g2_att= (const float*)d_in[12], *g2_b  = (const float*)d_in[13];
    const float *r1_Wl = (const float*)d_in[14], *r1_bl = (const float*)d_in[15];
    const float *r1_Wr = (const float*)d_in[16], *r1_br = (const float*)d_in[17];
    const float *r1_att= (const float*)d_in[18], *r1_b  = (const float*)d_in[19];
    const float *f1_Wl = (const float*)d_in[20], *f1_bl = (const float*)d_in[21];
    const float *f1_Wr = (const float*)d_in[22], *f1_br = (const float*)d_in[23];
    const float *f1_att= (const float*)d_in[24], *f1_b  = (const float*)d_in[25];
    const float *gru0_Wih = (const float*)d_in[26], *gru0_Whh = (const float*)d_in[27];
    const float *gru0_bih = (const float*)d_in[28], *gru0_bhh = (const float*)d_in[29];
    const float *gru1_Wih = (const float*)d_in[30], *gru1_Whh = (const float*)d_in[31];
    const float *gru1_bih = (const float*)d_in[32], *gru1_bhh = (const float*)d_in[33];
    const float *rec2_W = (const float*)d_in[34], *rec2_b = (const float*)d_in[35];
    const float *rec3_W = (const float*)d_in[36], *rec3_b = (const float*)d_in[37];
    const float *fore3_W= (const float*)d_in[38], *fore3_b= (const float*)d_in[39];

    // workspace layout
    char* ws = (char*)d_ws;
    int*   srcs = (int*)ws;                              // [32][1024][16] (2 MB)
    float* buf1 = (float*)(ws + (4u << 20));             // [32768,128] 16 MB
    float* buf2 = buf1 + (size_t)32768 * 128;            // [32768,128] 16 MB
    float* buf3 = buf2 + (size_t)32768 * 128;            // [32768,128] 16 MB
    float* buf4 = buf3 + (size_t)32768 * 128;            // [32768,128] 16 MB
    float* buf5 = buf4 + (size_t)32768 * 128;            // [32768,64]   8 MB
    float* buf6 = buf5 + (size_t)32768 * 64;             // [32768,32]   4 MB

    float* recon = (float*)d_out;                        // [31,1024,50]
    float* fore  = recon + (size_t)31 * 1024 * 50;       // [31,1024,50]
    float* E     = fore  + (size_t)31 * 1024 * 50;       // [32,1024,32]

    // 1. adjacency -> source lists (1024 blocks, deep-pipelined)
    k_srcs<<<Tt * 32, 256, 0, stream>>>(edge, srcs);

    // 2. GAT g1 (64 -> 64)
    k_lin2t<64, 128><<<1024, 256, 0, stream>>>(x, g1_Wl, g1_bl, g1_Wr, g1_br, buf1, buf2, 32768);
    k_gat64<false><<<8192, 256, 0, stream>>>(buf1, buf2, srcs, g1_att, g1_b, buf5, 32768,
                                             nullptr, nullptr, nullptr, nullptr);

    // 3. GAT g2 (64 -> 32)
    k_lin2t<64, 64><<<512, 256, 0, stream>>>(buf5, g2_Wl, g2_bl, g2_Wr, g2_br, buf1, buf2, 32768);
    k_gat32<<<4096, 256, 0, stream>>>(buf1, buf2, srcs, g2_att, g2_b, buf6, 16384);

    // 4. GRU stack: layer-0 input gates (parallel GEMM) + fused 2-layer serial
    k_lin96<<<2048, dim3(96, 2), 0, stream>>>(buf6, gru0_Wih, gru0_bih, buf1);   // GI0
    k_gru21<<<512, 64, 0, stream>>>(buf1, gru0_Whh, gru0_bhh,
                                    gru1_Wih, gru1_bih, gru1_Whh, gru1_bhh, E);

    // 5. r1+f1 projections in ONE kernel (E read once)
    k_lin4t<<<2048, 256, 0, stream>>>(E,
        r1_Wl, r1_bl, r1_Wr, r1_br, f1_Wl, f1_bl, f1_Wr, f1_br,
        buf1, buf2, buf3, buf4);

    // 6. reconstruct: GAT r1 + fused tanh(@rec2)@rec3 head
    k_gat64<true><<<7936, 256, 0, stream>>>(buf1, buf2, srcs + (size_t)KN * Nn, r1_att, r1_b, recon, 31744,
                                            rec2_W, rec2_b, rec3_W, rec3_b);

    // 7. forecast: GAT f1 + fused tanh(@rec2)@fore3 head
    k_gat64<true><<<7936, 256, 0, stream>>>(buf3, buf4, srcs, f1_att, f1_b, fore, 31744,
                                            rec2_W, rec2_b, fore3_W, fore3_b);

    (void)in_sizes; (void)n_in; (void)out_size; (void)ws_size;
}

// Round 11
// 295.377 us; speedup vs baseline: 1.1364x; 1.1364x over previous
//
#include <hip/hip_runtime.h>
#include <math.h>

static constexpr int Tt = 32;
static constexpr int Nn = 1024;
static constexpr int KN = 16;   // K + self

// ---------------------------------------------------------------------------
// Cross-lane primitives: DPP for xor1/xor2 (pure VALU), ds_swizzle otherwise.
// ---------------------------------------------------------------------------
template <int M>
__device__ __forceinline__ float lane_xor(float v) {
    if constexpr (M == 1)
        return __int_as_float(__builtin_amdgcn_mov_dpp(__float_as_int(v), 0xB1, 0xF, 0xF, true));
    else if constexpr (M == 2)
        return __int_as_float(__builtin_amdgcn_mov_dpp(__float_as_int(v), 0x4E, 0xF, 0xF, true));
    else
        return __shfl_xor(v, M);
}
__device__ __forceinline__ float bcastlane(float v, int l) {
    return __int_as_float(__builtin_amdgcn_readlane(__float_as_int(v), l));
}
__device__ __forceinline__ constexpr int rev4(int k) {
    return ((k & 1) << 3) | ((k & 2) << 1) | ((k & 4) >> 1) | ((k & 8) >> 3);
}
template <int NV, int M>
__device__ __forceinline__ void fstage(float* p, int lane) {
#pragma unroll
    for (int k2 = 0; k2 < NV / 2; ++k2) {
        float a_ = p[k2], b_ = p[k2 + NV / 2];
        float t_ = (lane & M) ? a_ : b_;
        float r_ = lane_xor<M>(t_);
        p[k2] = ((lane & M) ? b_ : a_) + r_;
    }
}
__device__ __forceinline__ float fold16(float* p, int lane) {
    fstage<16, 1>(p, lane); fstage<8, 2>(p, lane);
    fstage<4, 4>(p, lane);  fstage<2, 8>(p, lane);
    return p[0];
}
__device__ __forceinline__ float rmax16(float x) {
    x = fmaxf(x, lane_xor<1>(x)); x = fmaxf(x, lane_xor<2>(x));
    x = fmaxf(x, lane_xor<4>(x)); x = fmaxf(x, lane_xor<8>(x));
    return x;
}
__device__ __forceinline__ float rsum16(float x) {
    x += lane_xor<1>(x); x += lane_xor<2>(x);
    x += lane_xor<4>(x); x += lane_xor<8>(x);
    return x;
}

// ---------------------------------------------------------------------------
// 1. Recover source indices (order-free), layout srcs[t][n][16].
//    256 blocks (t x 8 stripes of 128 targets); 8-deep int4 pipeline.
// ---------------------------------------------------------------------------
__global__ __launch_bounds__(1024) void k_srcs(const int* __restrict__ edge,
                                               int* __restrict__ srcs)
{
    __shared__ int cnt[128];
    const int t    = blockIdx.x >> 3;
    const int tgt0 = (blockIdx.x & 7) << 7;
    const int x = threadIdx.x & 31;
    const int y = threadIdx.x >> 5;
    if (threadIdx.x < 128) cnt[threadIdx.x] = 0;
    __syncthreads();

    const int c0 = 4 * x;
    const int s0 = y * 32;
    const int* e = edge + (size_t)t * Nn * Nn + tgt0 + c0;

    for (int i0 = 0; i0 < 32; i0 += 8) {
        int4 v[8];
#pragma unroll
        for (int j = 0; j < 8; ++j)
            v[j] = *reinterpret_cast<const int4*>(e + (size_t)(s0 + i0 + j) * Nn);
#pragma unroll
        for (int j = 0; j < 8; ++j) {
            const int s = s0 + i0 + j;
            if (v[j].x) { int sl = atomicAdd(&cnt[c0],     1); if (sl < KN - 1) srcs[((size_t)t * Nn + tgt0 + c0)     * KN + sl] = s; }
            if (v[j].y) { int sl = atomicAdd(&cnt[c0 + 1], 1); if (sl < KN - 1) srcs[((size_t)t * Nn + tgt0 + c0 + 1) * KN + sl] = s; }
            if (v[j].z) { int sl = atomicAdd(&cnt[c0 + 2], 1); if (sl < KN - 1) srcs[((size_t)t * Nn + tgt0 + c0 + 2) * KN + sl] = s; }
            if (v[j].w) { int sl = atomicAdd(&cnt[c0 + 3], 1); if (sl < KN - 1) srcs[((size_t)t * Nn + tgt0 + c0 + 3) * KN + sl] = s; }
        }
    }
    if (threadIdx.x < 128)
        srcs[((size_t)t * Nn + tgt0 + threadIdx.x) * KN + (KN - 1)] = tgt0 + threadIdx.x;
}

// ---------------------------------------------------------------------------
// 2. Register-blocked dual linear, HEAD-INTERLEAVED float2 output (c, c+HC).
// ---------------------------------------------------------------------------
template <int FI, int FO>
__global__ __launch_bounds__(256) void k_lin2t(
    const float* __restrict__ X,
    const float* __restrict__ Wl, const float* __restrict__ bl,
    const float* __restrict__ Wr, const float* __restrict__ br,
    float* __restrict__ Yl, float* __restrict__ Yr, int rows)
{
    constexpr int HC = FO / 2;
    constexpr int RG = 256 / HC;
    constexpr int R  = 8;
    constexpr int BR = RG * R;
    constexpr int F4 = FI / 4;
    __shared__ float xs[BR][FI];

    const int tid  = threadIdx.x;
    const int c    = tid % HC;
    const int g    = tid / HC;
    const int row0 = blockIdx.x * BR;

#pragma unroll
    for (int idx = tid; idx < BR * F4; idx += 256) {
        int r = idx / F4, q = idx % F4;
        reinterpret_cast<float4*>(&xs[r][0])[q] =
            reinterpret_cast<const float4*>(X + (size_t)(row0 + r) * FI)[q];
    }
    __syncthreads();

    float al0[R], al1[R], ar0[R], ar1[R];
    const float bl0 = bl[c], bl1 = bl[c + HC], br0 = br[c], br1 = br[c + HC];
#pragma unroll
    for (int r = 0; r < R; ++r) { al0[r] = bl0; al1[r] = bl1; ar0[r] = br0; ar1[r] = br1; }

    const int rb = g * R;
#pragma unroll
    for (int i0 = 0; i0 < FI; i0 += 4) {
        float4 xv[R];
#pragma unroll
        for (int r = 0; r < R; ++r)
            xv[r] = *reinterpret_cast<const float4*>(&xs[rb + r][i0]);
#pragma unroll
        for (int j = 0; j < 4; ++j) {
            const float wl0 = Wl[(i0 + j) * FO + c];
            const float wl1 = Wl[(i0 + j) * FO + c + HC];
            const float wr0 = Wr[(i0 + j) * FO + c];
            const float wr1 = Wr[(i0 + j) * FO + c + HC];
#pragma unroll
            for (int r = 0; r < R; ++r) {
                const float xx = (&xv[r].x)[j];
                al0[r] = fmaf(xx, wl0, al0[r]);
                al1[r] = fmaf(xx, wl1, al1[r]);
                ar0[r] = fmaf(xx, wr0, ar0[r]);
                ar1[r] = fmaf(xx, wr1, ar1[r]);
            }
        }
    }
#pragma unroll
    for (int r = 0; r < R; ++r) {
        const size_t ro = (size_t)(row0 + rb + r) * FO;
        reinterpret_cast<float2*>(Yl + ro)[c] = make_float2(al0[r], al1[r]);
        reinterpret_cast<float2*>(Yr + ro)[c] = make_float2(ar0[r], ar1[r]);
    }
}

// ---------------------------------------------------------------------------
// 2b. Single linear to 96 cols (GRU input gates): Y = X@W^T + b.
// ---------------------------------------------------------------------------
__global__ __launch_bounds__(192) void k_lin96(
    const float* __restrict__ X, const float* __restrict__ W,
    const float* __restrict__ b, float* __restrict__ Y)
{
    __shared__ float wT[32 * 97];
    __shared__ float xs[16][32];

    const int tid = threadIdx.y * 96 + threadIdx.x;
    const int row0 = blockIdx.x * 16;

    for (int idx = tid; idx < 3072; idx += 192) {
        int c = idx >> 5, i = idx & 31;
        wT[i * 97 + c] = W[idx];
    }
    for (int idx = tid; idx < 128; idx += 192)
        reinterpret_cast<float4*>(xs)[idx] =
            reinterpret_cast<const float4*>(X + (size_t)row0 * 32)[idx];
    __syncthreads();

    const int c  = threadIdx.x;
    const int rb = threadIdx.y * 8;
    float acc[8];
    const float bc = b[c];
#pragma unroll
    for (int r = 0; r < 8; ++r) acc[r] = bc;

#pragma unroll
    for (int i = 0; i < 32; ++i) {
        const float w = wT[i * 97 + c];
#pragma unroll
        for (int r = 0; r < 8; ++r)
            acc[r] = fmaf(xs[rb + r][i], w, acc[r]);
    }
#pragma unroll
    for (int r = 0; r < 8; ++r)
        Y[(size_t)(row0 + rb + r) * 96 + c] = acc[r];
}

// ---------------------------------------------------------------------------
// 2c. Serial GRU layer: register weights, shfl broadcast, next-t gi prefetch.
// ---------------------------------------------------------------------------
__global__ __launch_bounds__(64) void k_gru1(
    const float* __restrict__ gi, const float* __restrict__ Whh,
    const float* __restrict__ bhh, float* __restrict__ E)
{
    const int d    = threadIdx.x & 31;
    const int node = blockIdx.x * 2 + (threadIdx.x >> 5);

    float wr_[32], wz_[32], wn_[32];
#pragma unroll
    for (int q = 0; q < 8; ++q) {
        *reinterpret_cast<float4*>(&wr_[q * 4]) =
            reinterpret_cast<const float4*>(Whh + (size_t)d * 32)[q];
        *reinterpret_cast<float4*>(&wz_[q * 4]) =
            reinterpret_cast<const float4*>(Whh + (size_t)(32 + d) * 32)[q];
        *reinterpret_cast<float4*>(&wn_[q * 4]) =
            reinterpret_cast<const float4*>(Whh + (size_t)(64 + d) * 32)[q];
    }
    const float br_ = bhh[d], bz_ = bhh[32 + d], bn_ = bhh[64 + d];

    size_t base = (size_t)node * 96 + d;
    float gr = gi[base], gz = gi[base + 32], gn = gi[base + 64];

    float h = 0.0f;
    for (int t = 0; t < Tt; ++t) {
        float grn = 0.f, gzn = 0.f, gnn = 0.f;
        if (t < Tt - 1) {
            const size_t nb = ((size_t)(t + 1) * Nn + node) * 96 + d;
            grn = gi[nb]; gzn = gi[nb + 32]; gnn = gi[nb + 64];
        }
        float ar = br_, az = bz_, an = bn_;
#pragma unroll
        for (int i = 0; i < 32; ++i) {
            const float hv = __shfl(h, i, 32);
            ar = fmaf(wr_[i], hv, ar);
            az = fmaf(wz_[i], hv, az);
            an = fmaf(wn_[i], hv, an);
        }
        const float r = __builtin_amdgcn_rcpf(1.0f + expf(-(gr + ar)));
        const float z = __builtin_amdgcn_rcpf(1.0f + expf(-(gz + az)));
        const float nn2 = tanhf(gn + r * an);
        h = (1.0f - z) * nn2 + z * h;
        E[((size_t)t * Nn + node) * 32 + d] = h;
        gr = grn; gz = gzn; gn = gnn;
    }
}

// ---------------------------------------------------------------------------
// Shared GATv2 C=64 wave body (fold structure): returns ELU'd result.
// ---------------------------------------------------------------------------
__device__ __forceinline__ float gat64_body(
    const float* __restrict__ gl, const float* __restrict__ gr,
    const int* __restrict__ srcs, const float* __restrict__ att,
    const float* __restrict__ bias, int wave, int lane)
{
    const int t = wave >> 10;
    const int n = wave & (Nn - 1);

    const float2 grl = reinterpret_cast<const float2*>(gr + (size_t)wave * 128)[lane];
    const float a0 = att[lane], a1 = att[64 + lane];

    const int4* sp = reinterpret_cast<const int4*>(srcs + ((size_t)t * Nn + n) * KN);
    const int4 sA = sp[0], sB = sp[1], sC = sp[2], sD = sp[3];
    int s[KN] = {sA.x, sA.y, sA.z, sA.w, sB.x, sB.y, sB.z, sB.w,
                 sC.x, sC.y, sC.z, sC.w, sD.x, sD.y, sD.z, sD.w};

    float2 g[KN];
    float p0[KN], p1[KN];
#pragma unroll
    for (int k = 0; k < KN; ++k) {
        g[k] = reinterpret_cast<const float2*>(gl + ((size_t)t * Nn + s[k]) * 128)[lane];
        float e0 = g[k].x + grl.x; e0 = fmaxf(e0, 0.2f * e0);
        float e1 = g[k].y + grl.y; e1 = fmaxf(e1, 0.2f * e1);
        p0[k] = e0 * a0; p1[k] = e1 * a1;
    }
    float lo0 = fold16(p0, lane);
    lo0 += lane_xor<16>(lo0); lo0 += __shfl_xor(lo0, 32);
    float lo1 = fold16(p1, lane);
    lo1 += lane_xor<16>(lo1); lo1 += __shfl_xor(lo1, 32);

    const float m0 = rmax16(lo0), m1 = rmax16(lo1);
    const float e0 = expf(lo0 - m0), e1 = expf(lo1 - m1);
    const float A0 = e0 * __builtin_amdgcn_rcpf(rsum16(e0));
    const float A1 = e1 * __builtin_amdgcn_rcpf(rsum16(e1));

    float acc0 = 0.0f, acc1 = 0.0f;
#pragma unroll
    for (int k = 0; k < KN; ++k) {
        acc0 = fmaf(bcastlane(A0, rev4(k)), g[k].x, acc0);
        acc1 = fmaf(bcastlane(A1, rev4(k)), g[k].y, acc1);
    }
    float res = 0.5f * (acc0 + acc1) + bias[lane];
    return res > 0.0f ? res : expm1f(res);
}

// ---------------------------------------------------------------------------
// 3. GATv2 C=64, plain output (g1).
// ---------------------------------------------------------------------------
__global__ __launch_bounds__(256) void k_gat64(
    const float* __restrict__ gl, const float* __restrict__ gr,
    const int* __restrict__ srcs, const float* __restrict__ att,
    const float* __restrict__ bias, float* __restrict__ out, int rows)
{
    const int lane = threadIdx.x & 63;
    const int w = threadIdx.x >> 6;
    const int gridB = rows >> 2;
    const int chunk = gridB >> 3;
    const int bid = blockIdx.x;
    const int lb = (bid & 7) * chunk + (bid >> 3);
    const int wave = lb * 4 + w;
    const float res = gat64_body(gl, gr, srcs, att, bias, wave, lane);
    out[(size_t)wave * 64 + lane] = res;
}

// ---------------------------------------------------------------------------
// 3h. Merged dual GAT+MLP-head: first 7936 blocks = reconstruct (r1/rec3),
//     next 7936 = forecast (f1/fore3). Shared W2/b2 (rec2). One launch.
// ---------------------------------------------------------------------------
__global__ __launch_bounds__(256) void k_gat64h2(
    const float* __restrict__ glA, const float* __restrict__ grA,
    const int* __restrict__ srcsA, const float* __restrict__ attA,
    const float* __restrict__ biasA, float* __restrict__ outA,
    const float* __restrict__ W3A, const float* __restrict__ b3A,
    const float* __restrict__ glB, const float* __restrict__ grB,
    const int* __restrict__ srcsB, const float* __restrict__ attB,
    const float* __restrict__ biasB, float* __restrict__ outB,
    const float* __restrict__ W3B, const float* __restrict__ b3B,
    const float* __restrict__ W2, const float* __restrict__ b2)
{
    __shared__ float hb[4][64];
    constexpr int rows = (Tt - 1) * Nn;      // 31744
    constexpr int gridH = rows >> 2;          // 7936
    constexpr int chunk = gridH >> 3;         // 992

    int bid = blockIdx.x;
    const bool second = bid >= gridH;
    if (second) bid -= gridH;

    const float* gl   = second ? glB   : glA;
    const float* gr   = second ? grB   : grA;
    const int*   srcs = second ? srcsB : srcsA;
    const float* att  = second ? attB  : attA;
    const float* bias = second ? biasB : biasA;
    float*       out  = second ? outB  : outA;
    const float* W3   = second ? W3B   : W3A;
    const float* b3   = second ? b3B   : b3A;

    const int lane = threadIdx.x & 63;
    const int w = threadIdx.x >> 6;
    const int lb = (bid & 7) * chunk + (bid >> 3);
    const int wave = lb * 4 + w;

    const float res = gat64_body(gl, gr, srcs, att, bias, wave, lane);

    // tanh(res @ W2 + b2) @ W3 + b3 -> out[wave][50]
    hb[w][lane] = res;
    __builtin_amdgcn_s_waitcnt(0);
    float acc = b2[lane];
#pragma unroll
    for (int i4 = 0; i4 < 16; ++i4) {
        const float4 hv = reinterpret_cast<const float4*>(&hb[w][0])[i4];
        acc = fmaf(hv.x, W2[(i4 * 4 + 0) * 64 + lane], acc);
        acc = fmaf(hv.y, W2[(i4 * 4 + 1) * 64 + lane], acc);
        acc = fmaf(hv.z, W2[(i4 * 4 + 2) * 64 + lane], acc);
        acc = fmaf(hv.w, W2[(i4 * 4 + 3) * 64 + lane], acc);
    }
    const float th = tanhf(acc);
    __builtin_amdgcn_s_waitcnt(0);
    hb[w][lane] = th;
    __builtin_amdgcn_s_waitcnt(0);
    if (lane < 50) {
        float a = b3[lane];
#pragma unroll
        for (int j4 = 0; j4 < 16; ++j4) {
            const float4 hv = reinterpret_cast<const float4*>(&hb[w][0])[j4];
            a = fmaf(hv.x, W3[(j4 * 4 + 0) * 50 + lane], a);
            a = fmaf(hv.y, W3[(j4 * 4 + 1) * 50 + lane], a);
            a = fmaf(hv.z, W3[(j4 * 4 + 2) * 50 + lane], a);
            a = fmaf(hv.w, W3[(j4 * 4 + 3) * 50 + lane], a);
        }
        out[(size_t)wave * 50 + lane] = a;
    }
}

// ---------------------------------------------------------------------------
// 3b. GATv2 C=32: two targets per wave, fold within halves.
// ---------------------------------------------------------------------------
__global__ __launch_bounds__(256) void k_gat32(
    const float* __restrict__ gl, const float* __restrict__ gr,
    const int* __restrict__ srcs, const float* __restrict__ att,
    const float* __restrict__ bias, float* __restrict__ out, int waves)
{
    const int lane = threadIdx.x & 63;
    const int w = threadIdx.x >> 6;
    const int gridB = waves >> 2;
    const int chunk = gridB >> 3;
    const int bid = blockIdx.x;
    const int lb = (bid & 7) * chunk + (bid >> 3);
    const int wv = lb * 4 + w;
    const int tgt = 2 * wv + (lane >> 5);
    const int t = tgt >> 10;
    const int n = tgt & (Nn - 1);
    const int c = lane & 31;

    const float2 grl = reinterpret_cast<const float2*>(gr + (size_t)tgt * 64)[c];
    const float a0 = att[c], a1 = att[32 + c];

    const int4* sp = reinterpret_cast<const int4*>(srcs + ((size_t)t * Nn + n) * KN);
    const int4 sA = sp[0], sB = sp[1], sC = sp[2], sD = sp[3];
    int s[KN] = {sA.x, sA.y, sA.z, sA.w, sB.x, sB.y, sB.z, sB.w,
                 sC.x, sC.y, sC.z, sC.w, sD.x, sD.y, sD.z, sD.w};

    float2 g[KN];
    float p0[KN], p1[KN];
#pragma unroll
    for (int k = 0; k < KN; ++k) {
        g[k] = reinterpret_cast<const float2*>(gl + ((size_t)t * Nn + s[k]) * 64)[c];
        float e0 = g[k].x + grl.x; e0 = fmaxf(e0, 0.2f * e0);
        float e1 = g[k].y + grl.y; e1 = fmaxf(e1, 0.2f * e1);
        p0[k] = e0 * a0; p1[k] = e1 * a1;
    }
    float lo0 = fold16(p0, lane); lo0 += lane_xor<16>(lo0);
    float lo1 = fold16(p1, lane); lo1 += lane_xor<16>(lo1);

    const float m0 = rmax16(lo0), m1 = rmax16(lo1);
    const float e0 = expf(lo0 - m0), e1 = expf(lo1 - m1);
    const float A0 = e0 * __builtin_amdgcn_rcpf(rsum16(e0));
    const float A1 = e1 * __builtin_amdgcn_rcpf(rsum16(e1));

    const float A0o = __shfl_xor(A0, 32);
    const float A1o = __shfl_xor(A1, 32);
    const bool loHalf = (lane < 32);

    float acc0 = 0.0f, acc1 = 0.0f;
#pragma unroll
    for (int k = 0; k < KN; ++k) {
        const float b0a = bcastlane(A0, rev4(k)), b0b = bcastlane(A0o, rev4(k));
        const float b1a = bcastlane(A1, rev4(k)), b1b = bcastlane(A1o, rev4(k));
        acc0 = fmaf(loHalf ? b0a : b0b, g[k].x, acc0);
        acc1 = fmaf(loHalf ? b1a : b1b, g[k].y, acc1);
    }
    float res = 0.5f * (acc0 + acc1) + bias[c];
    res = res > 0.0f ? res : expm1f(res);
    out[(size_t)tgt * 32 + c] = res;
}

// ---------------------------------------------------------------------------
extern "C" void kernel_launch(void* const* d_in, const int* in_sizes, int n_in,
                              void* d_out, int out_size, void* d_ws, size_t ws_size,
                              hipStream_t stream)
{
    const float* x    = (const float*)d_in[0];
    const int*   edge = (const int*)d_in[1];

    const float *g1_Wl = (const float*)d_in[2],  *g1_bl = (const float*)d_in[3];
    const float *g1_Wr = (const float*)d_in[4],  *g1_br = (const float*)d_in[5];
    const float *g1_att= (const float*)d_in[6],  *g1_b  = (const float*)d_in[7];
    const float *g2_Wl = (const float*)d_in[8],  *g2_bl = (const float*)d_in[9];
    const float *g2_Wr = (const float*)d_in[10], *g2_br = (const float*)d_in[11];
    const float *g2_att= (const float*)d_in[12], *g2_b  = (const float*)d_in[13];
    const float *r1_Wl = (const float*)d_in[14], *r1_bl = (const float*)d_in[15];
    const float *r1_Wr = (const float*)d_in[16], *r1_br = (const float*)d_in[17];
    const float *r1_att= (const float*)d_in[18], *r1_b  = (const float*)d_in[19];
    const float *f1_Wl = (const float*)d_in[20], *f1_bl = (const float*)d_in[21];
    const float *f1_Wr = (const float*)d_in[22], *f1_br = (const float*)d_in[23];
    const float *f1_att= (const float*)d_in[24], *f1_b  = (const float*)d_in[25];
    const float *gru0_Wih = (const float*)d_in[26], *gru0_Whh = (const float*)d_in[27];
    const float *gru0_bih = (const float*)d_in[28], *gru0_bhh = (const float*)d_in[29];
    const float *gru1_Wih = (const float*)d_in[30], *gru1_Whh = (const float*)d_in[31];
    const float *gru1_bih = (const float*)d_in[32], *gru1_bhh = (const float*)d_in[33];
    const float *rec2_W = (const float*)d_in[34], *rec2_b = (const float*)d_in[35];
    const float *rec3_W = (const float*)d_in[36], *rec3_b = (const float*)d_in[37];
    const float *fore3_W= (const float*)d_in[38], *fore3_b= (const float*)d_in[39];

    // workspace layout
    char* ws = (char*)d_ws;
    int*   srcs = (int*)ws;                              // [32][1024][16] (2 MB)
    float* buf1 = (float*)(ws + (4u << 20));             // [32768,128] 16 MB
    float* buf2 = buf1 + (size_t)32768 * 128;            // [32768,128] 16 MB
    float* buf3 = buf2 + (size_t)32768 * 128;            // [32768,128] 16 MB
    float* buf4 = buf3 + (size_t)32768 * 128;            // [32768,128] 16 MB
    float* buf5 = buf4 + (size_t)32768 * 128;            // [32768,64]   8 MB
    float* buf6 = buf5 + (size_t)32768 * 64;             // [32768,32]   4 MB

    float* recon = (float*)d_out;                        // [31,1024,50]
    float* fore  = recon + (size_t)31 * 1024 * 50;       // [31,1024,50]
    float* E     = fore  + (size_t)31 * 1024 * 50;       // [32,1024,32]

    // 1. adjacency -> source lists
    k_srcs<<<Tt * 8, 1024, 0, stream>>>(edge, srcs);

    // 2. GAT g1 (64 -> 64)
    k_lin2t<64, 128><<<1024, 256, 0, stream>>>(x, g1_Wl, g1_bl, g1_Wr, g1_br, buf1, buf2, 32768);
    k_gat64<<<8192, 256, 0, stream>>>(buf1, buf2, srcs, g1_att, g1_b, buf5, 32768);

    // 3. GAT g2 (64 -> 32)
    k_lin2t<64, 64><<<512, 256, 0, stream>>>(buf5, g2_Wl, g2_bl, g2_Wr, g2_br, buf1, buf2, 32768);
    k_gat32<<<4096, 256, 0, stream>>>(buf1, buf2, srcs, g2_att, g2_b, buf6, 16384);

    // 4. GRU stack: input gates (parallel GEMM) + serial layer, twice
    k_lin96<<<2048, dim3(96, 2), 0, stream>>>(buf6, gru0_Wih, gru0_bih, buf1);   // GI0
    k_gru1<<<512, 64, 0, stream>>>(buf1, gru0_Whh, gru0_bhh, buf5);              // E0
    k_lin96<<<2048, dim3(96, 2), 0, stream>>>(buf5, gru1_Wih, gru1_bih, buf2);   // GI1
    k_gru1<<<512, 64, 0, stream>>>(buf2, gru1_Whh, gru1_bhh, E);                 // E

    // 5. r1 and f1 projections (separate, R7 config)
    k_lin2t<32, 128><<<992, 256, 0, stream>>>(E + (size_t)Nn * 32, r1_Wl, r1_bl, r1_Wr, r1_br, buf1, buf2, 31744);
    k_lin2t<32, 128><<<992, 256, 0, stream>>>(E, f1_Wl, f1_bl, f1_Wr, f1_br, buf3, buf4, 31744);

    // 6. merged dual GAT+head: reconstruct + forecast in ONE launch
    k_gat64h2<<<15872, 256, 0, stream>>>(
        buf1, buf2, srcs + (size_t)KN * Nn, r1_att, r1_b, recon, rec3_W, rec3_b,
        buf3, buf4, srcs,                   f1_att, f1_b, fore,  fore3_W, fore3_b,
        rec2_W, rec2_b);

    (void)in_sizes; (void)n_in; (void)out_size; (void)ws_size;
}

// Round 12
// 289.856 us; speedup vs baseline: 1.1580x; 1.0190x over previous
//
#include <hip/hip_runtime.h>
#include <math.h>

static constexpr int Tt = 32;
static constexpr int Nn = 1024;
static constexpr int KN = 16;   // K + self

// ---------------------------------------------------------------------------
// Cross-lane primitives: DPP for xor1/xor2 (pure VALU), ds_swizzle otherwise.
// ---------------------------------------------------------------------------
template <int M>
__device__ __forceinline__ float lane_xor(float v) {
    if constexpr (M == 1)
        return __int_as_float(__builtin_amdgcn_mov_dpp(__float_as_int(v), 0xB1, 0xF, 0xF, true));
    else if constexpr (M == 2)
        return __int_as_float(__builtin_amdgcn_mov_dpp(__float_as_int(v), 0x4E, 0xF, 0xF, true));
    else
        return __shfl_xor(v, M);
}
__device__ __forceinline__ float bcastlane(float v, int l) {
    return __int_as_float(__builtin_amdgcn_readlane(__float_as_int(v), l));
}
__device__ __forceinline__ constexpr int rev4(int k) {
    return ((k & 1) << 3) | ((k & 2) << 1) | ((k & 4) >> 1) | ((k & 8) >> 3);
}
template <int NV, int M>
__device__ __forceinline__ void fstage(float* p, int lane) {
#pragma unroll
    for (int k2 = 0; k2 < NV / 2; ++k2) {
        float a_ = p[k2], b_ = p[k2 + NV / 2];
        float t_ = (lane & M) ? a_ : b_;
        float r_ = lane_xor<M>(t_);
        p[k2] = ((lane & M) ? b_ : a_) + r_;
    }
}
__device__ __forceinline__ float fold16(float* p, int lane) {
    fstage<16, 1>(p, lane); fstage<8, 2>(p, lane);
    fstage<4, 4>(p, lane);  fstage<2, 8>(p, lane);
    return p[0];
}
__device__ __forceinline__ float rmax16(float x) {
    x = fmaxf(x, lane_xor<1>(x)); x = fmaxf(x, lane_xor<2>(x));
    x = fmaxf(x, lane_xor<4>(x)); x = fmaxf(x, lane_xor<8>(x));
    return x;
}
__device__ __forceinline__ float rsum16(float x) {
    x += lane_xor<1>(x); x += lane_xor<2>(x);
    x += lane_xor<4>(x); x += lane_xor<8>(x);
    return x;
}

// ---------------------------------------------------------------------------
// 1. Recover source indices (order-free), layout srcs[t][n][16].
//    256 blocks (t x 8 stripes of 128 targets); 8-deep int4 pipeline.
// ---------------------------------------------------------------------------
__global__ __launch_bounds__(1024) void k_srcs(const int* __restrict__ edge,
                                               int* __restrict__ srcs)
{
    __shared__ int cnt[128];
    const int t    = blockIdx.x >> 3;
    const int tgt0 = (blockIdx.x & 7) << 7;
    const int x = threadIdx.x & 31;
    const int y = threadIdx.x >> 5;
    if (threadIdx.x < 128) cnt[threadIdx.x] = 0;
    __syncthreads();

    const int c0 = 4 * x;
    const int s0 = y * 32;
    const int* e = edge + (size_t)t * Nn * Nn + tgt0 + c0;

    for (int i0 = 0; i0 < 32; i0 += 8) {
        int4 v[8];
#pragma unroll
        for (int j = 0; j < 8; ++j)
            v[j] = *reinterpret_cast<const int4*>(e + (size_t)(s0 + i0 + j) * Nn);
#pragma unroll
        for (int j = 0; j < 8; ++j) {
            const int s = s0 + i0 + j;
            if (v[j].x) { int sl = atomicAdd(&cnt[c0],     1); if (sl < KN - 1) srcs[((size_t)t * Nn + tgt0 + c0)     * KN + sl] = s; }
            if (v[j].y) { int sl = atomicAdd(&cnt[c0 + 1], 1); if (sl < KN - 1) srcs[((size_t)t * Nn + tgt0 + c0 + 1) * KN + sl] = s; }
            if (v[j].z) { int sl = atomicAdd(&cnt[c0 + 2], 1); if (sl < KN - 1) srcs[((size_t)t * Nn + tgt0 + c0 + 2) * KN + sl] = s; }
            if (v[j].w) { int sl = atomicAdd(&cnt[c0 + 3], 1); if (sl < KN - 1) srcs[((size_t)t * Nn + tgt0 + c0 + 3) * KN + sl] = s; }
        }
    }
    if (threadIdx.x < 128)
        srcs[((size_t)t * Nn + tgt0 + threadIdx.x) * KN + (KN - 1)] = tgt0 + threadIdx.x;
}

// ---------------------------------------------------------------------------
// 2. Register-blocked dual linear, HEAD-INTERLEAVED float2 output (c, c+HC).
// ---------------------------------------------------------------------------
template <int FI, int FO>
__global__ __launch_bounds__(256) void k_lin2t(
    const float* __restrict__ X,
    const float* __restrict__ Wl, const float* __restrict__ bl,
    const float* __restrict__ Wr, const float* __restrict__ br,
    float* __restrict__ Yl, float* __restrict__ Yr, int rows)
{
    constexpr int HC = FO / 2;
    constexpr int RG = 256 / HC;
    constexpr int R  = 8;
    constexpr int BR = RG * R;
    constexpr int F4 = FI / 4;
    __shared__ float xs[BR][FI];

    const int tid  = threadIdx.x;
    const int c    = tid % HC;
    const int g    = tid / HC;
    const int row0 = blockIdx.x * BR;

#pragma unroll
    for (int idx = tid; idx < BR * F4; idx += 256) {
        int r = idx / F4, q = idx % F4;
        reinterpret_cast<float4*>(&xs[r][0])[q] =
            reinterpret_cast<const float4*>(X + (size_t)(row0 + r) * FI)[q];
    }
    __syncthreads();

    float al0[R], al1[R], ar0[R], ar1[R];
    const float bl0 = bl[c], bl1 = bl[c + HC], br0 = br[c], br1 = br[c + HC];
#pragma unroll
    for (int r = 0; r < R; ++r) { al0[r] = bl0; al1[r] = bl1; ar0[r] = br0; ar1[r] = br1; }

    const int rb = g * R;
#pragma unroll
    for (int i0 = 0; i0 < FI; i0 += 4) {
        float4 xv[R];
#pragma unroll
        for (int r = 0; r < R; ++r)
            xv[r] = *reinterpret_cast<const float4*>(&xs[rb + r][i0]);
#pragma unroll
        for (int j = 0; j < 4; ++j) {
            const float wl0 = Wl[(i0 + j) * FO + c];
            const float wl1 = Wl[(i0 + j) * FO + c + HC];
            const float wr0 = Wr[(i0 + j) * FO + c];
            const float wr1 = Wr[(i0 + j) * FO + c + HC];
#pragma unroll
            for (int r = 0; r < R; ++r) {
                const float xx = (&xv[r].x)[j];
                al0[r] = fmaf(xx, wl0, al0[r]);
                al1[r] = fmaf(xx, wl1, al1[r]);
                ar0[r] = fmaf(xx, wr0, ar0[r]);
                ar1[r] = fmaf(xx, wr1, ar1[r]);
            }
        }
    }
#pragma unroll
    for (int r = 0; r < R; ++r) {
        const size_t ro = (size_t)(row0 + rb + r) * FO;
        reinterpret_cast<float2*>(Yl + ro)[c] = make_float2(al0[r], al1[r]);
        reinterpret_cast<float2*>(Yr + ro)[c] = make_float2(ar0[r], ar1[r]);
    }
}

// ---------------------------------------------------------------------------
// 2m. Merged r1+f1 projection (one launch, pointer select): first 992 blocks
//     project E[1:] with r1 weights, next 992 project E[:-1] with f1 weights.
// ---------------------------------------------------------------------------
__global__ __launch_bounds__(256) void k_lin2td(
    const float* __restrict__ E,
    const float* __restrict__ WlA, const float* __restrict__ blA,
    const float* __restrict__ WrA, const float* __restrict__ brA,
    float* __restrict__ YlA, float* __restrict__ YrA,
    const float* __restrict__ WlB, const float* __restrict__ blB,
    const float* __restrict__ WrB, const float* __restrict__ brB,
    float* __restrict__ YlB, float* __restrict__ YrB)
{
    constexpr int FI = 32, FO = 128, HC = 64, R = 8, BR = 32, F4 = FI / 4;
    __shared__ float xs[BR][FI];

    int bid = blockIdx.x;
    const bool second = bid >= 992;
    if (second) bid -= 992;

    const float* X  = second ? E   : (E + (size_t)Nn * FI);
    const float* Wl = second ? WlB : WlA;
    const float* bl = second ? blB : blA;
    const float* Wr = second ? WrB : WrA;
    const float* br = second ? brB : brA;
    float* Yl = second ? YlB : YlA;
    float* Yr = second ? YrB : YrA;

    const int tid  = threadIdx.x;
    const int c    = tid % HC;
    const int g    = tid / HC;
    const int row0 = bid * BR;

#pragma unroll
    for (int idx = tid; idx < BR * F4; idx += 256) {
        int r = idx / F4, q = idx % F4;
        reinterpret_cast<float4*>(&xs[r][0])[q] =
            reinterpret_cast<const float4*>(X + (size_t)(row0 + r) * FI)[q];
    }
    __syncthreads();

    float al0[R], al1[R], ar0[R], ar1[R];
    const float bl0 = bl[c], bl1 = bl[c + HC], br0 = br[c], br1 = br[c + HC];
#pragma unroll
    for (int r = 0; r < R; ++r) { al0[r] = bl0; al1[r] = bl1; ar0[r] = br0; ar1[r] = br1; }

    const int rb = g * R;
#pragma unroll
    for (int i0 = 0; i0 < FI; i0 += 4) {
        float4 xv[R];
#pragma unroll
        for (int r = 0; r < R; ++r)
            xv[r] = *reinterpret_cast<const float4*>(&xs[rb + r][i0]);
#pragma unroll
        for (int j = 0; j < 4; ++j) {
            const float wl0 = Wl[(i0 + j) * FO + c];
            const float wl1 = Wl[(i0 + j) * FO + c + HC];
            const float wr0 = Wr[(i0 + j) * FO + c];
            const float wr1 = Wr[(i0 + j) * FO + c + HC];
#pragma unroll
            for (int r = 0; r < R; ++r) {
                const float xx = (&xv[r].x)[j];
                al0[r] = fmaf(xx, wl0, al0[r]);
                al1[r] = fmaf(xx, wl1, al1[r]);
                ar0[r] = fmaf(xx, wr0, ar0[r]);
                ar1[r] = fmaf(xx, wr1, ar1[r]);
            }
        }
    }
#pragma unroll
    for (int r = 0; r < R; ++r) {
        const size_t ro = (size_t)(row0 + rb + r) * FO;
        reinterpret_cast<float2*>(Yl + ro)[c] = make_float2(al0[r], al1[r]);
        reinterpret_cast<float2*>(Yr + ro)[c] = make_float2(ar0[r], ar1[r]);
    }
}

// ---------------------------------------------------------------------------
// 2b. Single linear to 96 cols (GRU input gates): Y = X@W^T + b.
// ---------------------------------------------------------------------------
__global__ __launch_bounds__(192) void k_lin96(
    const float* __restrict__ X, const float* __restrict__ W,
    const float* __restrict__ b, float* __restrict__ Y)
{
    __shared__ float wT[32 * 97];
    __shared__ float xs[16][32];

    const int tid = threadIdx.y * 96 + threadIdx.x;
    const int row0 = blockIdx.x * 16;

    for (int idx = tid; idx < 3072; idx += 192) {
        int c = idx >> 5, i = idx & 31;
        wT[i * 97 + c] = W[idx];
    }
    for (int idx = tid; idx < 128; idx += 192)
        reinterpret_cast<float4*>(xs)[idx] =
            reinterpret_cast<const float4*>(X + (size_t)row0 * 32)[idx];
    __syncthreads();

    const int c  = threadIdx.x;
    const int rb = threadIdx.y * 8;
    float acc[8];
    const float bc = b[c];
#pragma unroll
    for (int r = 0; r < 8; ++r) acc[r] = bc;

#pragma unroll
    for (int i = 0; i < 32; ++i) {
        const float w = wT[i * 97 + c];
#pragma unroll
        for (int r = 0; r < 8; ++r)
            acc[r] = fmaf(xs[rb + r][i], w, acc[r]);
    }
#pragma unroll
    for (int r = 0; r < 8; ++r)
        Y[(size_t)(row0 + rb + r) * 96 + c] = acc[r];
}

// ---------------------------------------------------------------------------
// 2c. Serial GRU layer: register weights, shfl broadcast, next-t gi prefetch.
// ---------------------------------------------------------------------------
__global__ __launch_bounds__(64) void k_gru1(
    const float* __restrict__ gi, const float* __restrict__ Whh,
    const float* __restrict__ bhh, float* __restrict__ E)
{
    const int d    = threadIdx.x & 31;
    const int node = blockIdx.x * 2 + (threadIdx.x >> 5);

    float wr_[32], wz_[32], wn_[32];
#pragma unroll
    for (int q = 0; q < 8; ++q) {
        *reinterpret_cast<float4*>(&wr_[q * 4]) =
            reinterpret_cast<const float4*>(Whh + (size_t)d * 32)[q];
        *reinterpret_cast<float4*>(&wz_[q * 4]) =
            reinterpret_cast<const float4*>(Whh + (size_t)(32 + d) * 32)[q];
        *reinterpret_cast<float4*>(&wn_[q * 4]) =
            reinterpret_cast<const float4*>(Whh + (size_t)(64 + d) * 32)[q];
    }
    const float br_ = bhh[d], bz_ = bhh[32 + d], bn_ = bhh[64 + d];

    size_t base = (size_t)node * 96 + d;
    float gr = gi[base], gz = gi[base + 32], gn = gi[base + 64];

    float h = 0.0f;
    for (int t = 0; t < Tt; ++t) {
        float grn = 0.f, gzn = 0.f, gnn = 0.f;
        if (t < Tt - 1) {
            const size_t nb = ((size_t)(t + 1) * Nn + node) * 96 + d;
            grn = gi[nb]; gzn = gi[nb + 32]; gnn = gi[nb + 64];
        }
        float ar = br_, az = bz_, an = bn_;
#pragma unroll
        for (int i = 0; i < 32; ++i) {
            const float hv = __shfl(h, i, 32);
            ar = fmaf(wr_[i], hv, ar);
            az = fmaf(wz_[i], hv, az);
            an = fmaf(wn_[i], hv, an);
        }
        const float r = __builtin_amdgcn_rcpf(1.0f + expf(-(gr + ar)));
        const float z = __builtin_amdgcn_rcpf(1.0f + expf(-(gz + az)));
        const float nn2 = tanhf(gn + r * an);
        h = (1.0f - z) * nn2 + z * h;
        E[((size_t)t * Nn + node) * 32 + d] = h;
        gr = grn; gz = gzn; gn = gnn;
    }
}

// ---------------------------------------------------------------------------
// Shared GATv2 C=64 wave body (fold structure): returns ELU'd result.
// ---------------------------------------------------------------------------
__device__ __forceinline__ float gat64_body(
    const float* __restrict__ gl, const float* __restrict__ gr,
    const int* __restrict__ srcs, const float* __restrict__ att,
    const float* __restrict__ bias, int wave, int lane)
{
    const int t = wave >> 10;
    const int n = wave & (Nn - 1);

    const float2 grl = reinterpret_cast<const float2*>(gr + (size_t)wave * 128)[lane];
    const float a0 = att[lane], a1 = att[64 + lane];

    const int4* sp = reinterpret_cast<const int4*>(srcs + ((size_t)t * Nn + n) * KN);
    const int4 sA = sp[0], sB = sp[1], sC = sp[2], sD = sp[3];
    int s[KN] = {sA.x, sA.y, sA.z, sA.w, sB.x, sB.y, sB.z, sB.w,
                 sC.x, sC.y, sC.z, sC.w, sD.x, sD.y, sD.z, sD.w};

    float2 g[KN];
    float p0[KN], p1[KN];
#pragma unroll
    for (int k = 0; k < KN; ++k) {
        g[k] = reinterpret_cast<const float2*>(gl + ((size_t)t * Nn + s[k]) * 128)[lane];
        float e0 = g[k].x + grl.x; e0 = fmaxf(e0, 0.2f * e0);
        float e1 = g[k].y + grl.y; e1 = fmaxf(e1, 0.2f * e1);
        p0[k] = e0 * a0; p1[k] = e1 * a1;
    }
    float lo0 = fold16(p0, lane);
    lo0 += lane_xor<16>(lo0); lo0 += __shfl_xor(lo0, 32);
    float lo1 = fold16(p1, lane);
    lo1 += lane_xor<16>(lo1); lo1 += __shfl_xor(lo1, 32);

    const float m0 = rmax16(lo0), m1 = rmax16(lo1);
    const float e0 = expf(lo0 - m0), e1 = expf(lo1 - m1);
    const float A0 = e0 * __builtin_amdgcn_rcpf(rsum16(e0));
    const float A1 = e1 * __builtin_amdgcn_rcpf(rsum16(e1));

    float acc0 = 0.0f, acc1 = 0.0f;
#pragma unroll
    for (int k = 0; k < KN; ++k) {
        acc0 = fmaf(bcastlane(A0, rev4(k)), g[k].x, acc0);
        acc1 = fmaf(bcastlane(A1, rev4(k)), g[k].y, acc1);
    }
    float res = 0.5f * (acc0 + acc1) + bias[lane];
    return res > 0.0f ? res : expm1f(res);
}

// ---------------------------------------------------------------------------
// 3. GATv2 C=64, plain output (g1).
// ---------------------------------------------------------------------------
__global__ __launch_bounds__(256) void k_gat64(
    const float* __restrict__ gl, const float* __restrict__ gr,
    const int* __restrict__ srcs, const float* __restrict__ att,
    const float* __restrict__ bias, float* __restrict__ out, int rows)
{
    const int lane = threadIdx.x & 63;
    const int w = threadIdx.x >> 6;
    const int gridB = rows >> 2;
    const int chunk = gridB >> 3;
    const int bid = blockIdx.x;
    const int lb = (bid & 7) * chunk + (bid >> 3);
    const int wave = lb * 4 + w;
    const float res = gat64_body(gl, gr, srcs, att, bias, wave, lane);
    out[(size_t)wave * 64 + lane] = res;
}

// ---------------------------------------------------------------------------
// 3h. Merged dual GAT+MLP-head. hb is SAME-WAVE LDS (in-order pipe) — no
//     explicit waitcnt: compiler inserts precise lgkmcnt before each use,
//     leaving global W2/W3 loads free to prefetch under compute.
// ---------------------------------------------------------------------------
__global__ __launch_bounds__(256) void k_gat64h2(
    const float* __restrict__ glA, const float* __restrict__ grA,
    const int* __restrict__ srcsA, const float* __restrict__ attA,
    const float* __restrict__ biasA, float* __restrict__ outA,
    const float* __restrict__ W3A, const float* __restrict__ b3A,
    const float* __restrict__ glB, const float* __restrict__ grB,
    const int* __restrict__ srcsB, const float* __restrict__ attB,
    const float* __restrict__ biasB, float* __restrict__ outB,
    const float* __restrict__ W3B, const float* __restrict__ b3B,
    const float* __restrict__ W2, const float* __restrict__ b2)
{
    __shared__ float hb[4][64];
    constexpr int rows = (Tt - 1) * Nn;      // 31744
    constexpr int gridH = rows >> 2;          // 7936
    constexpr int chunk = gridH >> 3;         // 992

    int bid = blockIdx.x;
    const bool second = bid >= gridH;
    if (second) bid -= gridH;

    const float* gl   = second ? glB   : glA;
    const float* gr   = second ? grB   : grA;
    const int*   srcs = second ? srcsB : srcsA;
    const float* att  = second ? attB  : attA;
    const float* bias = second ? biasB : biasA;
    float*       out  = second ? outB  : outA;
    const float* W3   = second ? W3B   : W3A;
    const float* b3   = second ? b3B   : b3A;

    const int lane = threadIdx.x & 63;
    const int w = threadIdx.x >> 6;
    const int lb = (bid & 7) * chunk + (bid >> 3);
    const int wave = lb * 4 + w;

    const float res = gat64_body(gl, gr, srcs, att, bias, wave, lane);

    // tanh(res @ W2 + b2) @ W3 + b3 -> out[wave][50]   (same-wave LDS only)
    hb[w][lane] = res;
    float acc = b2[lane];
#pragma unroll
    for (int i4 = 0; i4 < 16; ++i4) {
        const float4 hv = reinterpret_cast<const float4*>(&hb[w][0])[i4];
        acc = fmaf(hv.x, W2[(i4 * 4 + 0) * 64 + lane], acc);
        acc = fmaf(hv.y, W2[(i4 * 4 + 1) * 64 + lane], acc);
        acc = fmaf(hv.z, W2[(i4 * 4 + 2) * 64 + lane], acc);
        acc = fmaf(hv.w, W2[(i4 * 4 + 3) * 64 + lane], acc);
    }
    const float th = tanhf(acc);
    hb[w][lane] = th;
    if (lane < 50) {
        float a = b3[lane];
#pragma unroll
        for (int j4 = 0; j4 < 16; ++j4) {
            const float4 hv = reinterpret_cast<const float4*>(&hb[w][0])[j4];
            a = fmaf(hv.x, W3[(j4 * 4 + 0) * 50 + lane], a);
            a = fmaf(hv.y, W3[(j4 * 4 + 1) * 50 + lane], a);
            a = fmaf(hv.z, W3[(j4 * 4 + 2) * 50 + lane], a);
            a = fmaf(hv.w, W3[(j4 * 4 + 3) * 50 + lane], a);
        }
        out[(size_t)wave * 50 + lane] = a;
    }
}

// ---------------------------------------------------------------------------
// 3b. GATv2 C=32: two targets per wave, fold within halves.
// ---------------------------------------------------------------------------
__global__ __launch_bounds__(256) void k_gat32(
    const float* __restrict__ gl, const float* __restrict__ gr,
    const int* __restrict__ srcs, const float* __restrict__ att,
    const float* __restrict__ bias, float* __restrict__ out, int waves)
{
    const int lane = threadIdx.x & 63;
    const int w = threadIdx.x >> 6;
    const int gridB = waves >> 2;
    const int chunk = gridB >> 3;
    const int bid = blockIdx.x;
    const int lb = (bid & 7) * chunk + (bid >> 3);
    const int wv = lb * 4 + w;
    const int tgt = 2 * wv + (lane >> 5);
    const int t = tgt >> 10;
    const int n = tgt & (Nn - 1);
    const int c = lane & 31;

    const float2 grl = reinterpret_cast<const float2*>(gr + (size_t)tgt * 64)[c];
    const float a0 = att[c], a1 = att[32 + c];

    const int4* sp = reinterpret_cast<const int4*>(srcs + ((size_t)t * Nn + n) * KN);
    const int4 sA = sp[0], sB = sp[1], sC = sp[2], sD = sp[3];
    int s[KN] = {sA.x, sA.y, sA.z, sA.w, sB.x, sB.y, sB.z, sB.w,
                 sC.x, sC.y, sC.z, sC.w, sD.x, sD.y, sD.z, sD.w};

    float2 g[KN];
    float p0[KN], p1[KN];
#pragma unroll
    for (int k = 0; k < KN; ++k) {
        g[k] = reinterpret_cast<const float2*>(gl + ((size_t)t * Nn + s[k]) * 64)[c];
        float e0 = g[k].x + grl.x; e0 = fmaxf(e0, 0.2f * e0);
        float e1 = g[k].y + grl.y; e1 = fmaxf(e1, 0.2f * e1);
        p0[k] = e0 * a0; p1[k] = e1 * a1;
    }
    float lo0 = fold16(p0, lane); lo0 += lane_xor<16>(lo0);
    float lo1 = fold16(p1, lane); lo1 += lane_xor<16>(lo1);

    const float m0 = rmax16(lo0), m1 = rmax16(lo1);
    const float e0 = expf(lo0 - m0), e1 = expf(lo1 - m1);
    const float A0 = e0 * __builtin_amdgcn_rcpf(rsum16(e0));
    const float A1 = e1 * __builtin_amdgcn_rcpf(rsum16(e1));

    const float A0o = __shfl_xor(A0, 32);
    const float A1o = __shfl_xor(A1, 32);
    const bool loHalf = (lane < 32);

    float acc0 = 0.0f, acc1 = 0.0f;
#pragma unroll
    for (int k = 0; k < KN; ++k) {
        const float b0a = bcastlane(A0, rev4(k)), b0b = bcastlane(A0o, rev4(k));
        const float b1a = bcastlane(A1, rev4(k)), b1b = bcastlane(A1o, rev4(k));
        acc0 = fmaf(loHalf ? b0a : b0b, g[k].x, acc0);
        acc1 = fmaf(loHalf ? b1a : b1b, g[k].y, acc1);
    }
    float res = 0.5f * (acc0 + acc1) + bias[c];
    res = res > 0.0f ? res : expm1f(res);
    out[(size_t)tgt * 32 + c] = res;
}

// ---------------------------------------------------------------------------
extern "C" void kernel_launch(void* const* d_in, const int* in_sizes, int n_in,
                              void* d_out, int out_size, void* d_ws, size_t ws_size,
                              hipStream_t stream)
{
    const float* x    = (const float*)d_in[0];
    const int*   edge = (const int*)d_in[1];

    const float *g1_Wl = (const float*)d_in[2],  *g1_bl = (const float*)d_in[3];
    const float *g1_Wr = (const float*)d_in[4],  *g1_br = (const float*)d_in[5];
    const float *g1_att= (const float*)d_in[6],  *g1_b  = (const float*)d_in[7];
    const float *g2_Wl = (const float*)d_in[8],  *g2_bl = (const float*)d_in[9];
    const float *g2_Wr = (const float*)d_in[10], *g2_br = (const float*)d_in[11];
    const float *g2_att= (const float*)d_in[12], *g2_b  = (const float*)d_in[13];
    const float *r1_Wl = (const float*)d_in[14], *r1_bl = (const float*)d_in[15];
    const float *r1_Wr = (const float*)d_in[16], *r1_br = (const float*)d_in[17];
    const float *r1_att= (const float*)d_in[18], *r1_b  = (const float*)d_in[19];
    const float *f1_Wl = (const float*)d_in[20], *f1_bl = (const float*)d_in[21];
    const float *f1_Wr = (const float*)d_in[22], *f1_br = (const float*)d_in[23];
    const float *f1_att= (const float*)d_in[24], *f1_b  = (const float*)d_in[25];
    const float *gru0_Wih = (const float*)d_in[26], *gru0_Whh = (const float*)d_in[27];
    const float *gru0_bih = (const float*)d_in[28], *gru0_bhh = (const float*)d_in[29];
    const float *gru1_Wih = (const float*)d_in[30], *gru1_Whh = (const float*)d_in[31];
    const float *gru1_bih = (const float*)d_in[32], *gru1_bhh = (const float*)d_in[33];
    const float *rec2_W = (const float*)d_in[34], *rec2_b = (const float*)d_in[35];
    const float *rec3_W = (const float*)d_in[36], *rec3_b = (const float*)d_in[37];
    const float *fore3_W= (const float*)d_in[38], *fore3_b= (const float*)d_in[39];

    // workspace layout
    char* ws = (char*)d_ws;
    int*   srcs = (int*)ws;                              // [32][1024][16] (2 MB)
    float* buf1 = (float*)(ws + (4u << 20));             // [32768,128] 16 MB
    float* buf2 = buf1 + (size_t)32768 * 128;            // [32768,128] 16 MB
    float* buf3 = buf2 + (size_t)32768 * 128;            // [32768,128] 16 MB
    float* buf4 = buf3 + (size_t)32768 * 128;            // [32768,128] 16 MB
    float* buf5 = buf4 + (size_t)32768 * 128;            // [32768,64]   8 MB
    float* buf6 = buf5 + (size_t)32768 * 64;             // [32768,32]   4 MB

    float* recon = (float*)d_out;                        // [31,1024,50]
    float* fore  = recon + (size_t)31 * 1024 * 50;       // [31,1024,50]
    float* E     = fore  + (size_t)31 * 1024 * 50;       // [32,1024,32]

    // 1. adjacency -> source lists
    k_srcs<<<Tt * 8, 1024, 0, stream>>>(edge, srcs);

    // 2. GAT g1 (64 -> 64)
    k_lin2t<64, 128><<<1024, 256, 0, stream>>>(x, g1_Wl, g1_bl, g1_Wr, g1_br, buf1, buf2, 32768);
    k_gat64<<<8192, 256, 0, stream>>>(buf1, buf2, srcs, g1_att, g1_b, buf5, 32768);

    // 3. GAT g2 (64 -> 32)
    k_lin2t<64, 64><<<512, 256, 0, stream>>>(buf5, g2_Wl, g2_bl, g2_Wr, g2_br, buf1, buf2, 32768);
    k_gat32<<<4096, 256, 0, stream>>>(buf1, buf2, srcs, g2_att, g2_b, buf6, 16384);

    // 4. GRU stack: input gates (parallel GEMM) + serial layer, twice
    k_lin96<<<2048, dim3(96, 2), 0, stream>>>(buf6, gru0_Wih, gru0_bih, buf1);   // GI0
    k_gru1<<<512, 64, 0, stream>>>(buf1, gru0_Whh, gru0_bhh, buf5);              // E0
    k_lin96<<<2048, dim3(96, 2), 0, stream>>>(buf5, gru1_Wih, gru1_bih, buf2);   // GI1
    k_gru1<<<512, 64, 0, stream>>>(buf2, gru1_Whh, gru1_bhh, E);                 // E

    // 5. r1+f1 projections in one launch (pointer select)
    k_lin2td<<<1984, 256, 0, stream>>>(E,
        r1_Wl, r1_bl, r1_Wr, r1_br, buf1, buf2,
        f1_Wl, f1_bl, f1_Wr, f1_br, buf3, buf4);

    // 6. merged dual GAT+head: reconstruct + forecast in ONE launch
    k_gat64h2<<<15872, 256, 0, stream>>>(
        buf1, buf2, srcs + (size_t)KN * Nn, r1_att, r1_b, recon, rec3_W, rec3_b,
        buf3, buf4, srcs,                   f1_att, f1_b, fore,  fore3_W, fore3_b,
        rec2_W, rec2_b);

    (void)in_sizes; (void)n_in; (void)out_size; (void)ws_size;
}

// Round 13
// 288.173 us; speedup vs baseline: 1.1648x; 1.0058x over previous
//
#include <hip/hip_runtime.h>
#include <math.h>

static constexpr int Tt = 32;
static constexpr int Nn = 1024;
static constexpr int KN = 16;   // K + self

// ---------------------------------------------------------------------------
// Cross-lane primitives: DPP for xor1/xor2 (pure VALU), ds_swizzle otherwise.
// ---------------------------------------------------------------------------
template <int M>
__device__ __forceinline__ float lane_xor(float v) {
    if constexpr (M == 1)
        return __int_as_float(__builtin_amdgcn_mov_dpp(__float_as_int(v), 0xB1, 0xF, 0xF, true));
    else if constexpr (M == 2)
        return __int_as_float(__builtin_amdgcn_mov_dpp(__float_as_int(v), 0x4E, 0xF, 0xF, true));
    else
        return __shfl_xor(v, M);
}
__device__ __forceinline__ float bcastlane(float v, int l) {
    return __int_as_float(__builtin_amdgcn_readlane(__float_as_int(v), l));
}
__device__ __forceinline__ constexpr int rev4(int k) {
    return ((k & 1) << 3) | ((k & 2) << 1) | ((k & 4) >> 1) | ((k & 8) >> 3);
}
template <int NV, int M>
__device__ __forceinline__ void fstage(float* p, int lane) {
#pragma unroll
    for (int k2 = 0; k2 < NV / 2; ++k2) {
        float a_ = p[k2], b_ = p[k2 + NV / 2];
        float t_ = (lane & M) ? a_ : b_;
        float r_ = lane_xor<M>(t_);
        p[k2] = ((lane & M) ? b_ : a_) + r_;
    }
}
__device__ __forceinline__ float fold16(float* p, int lane) {
    fstage<16, 1>(p, lane); fstage<8, 2>(p, lane);
    fstage<4, 4>(p, lane);  fstage<2, 8>(p, lane);
    return p[0];
}
__device__ __forceinline__ float rmax16(float x) {
    x = fmaxf(x, lane_xor<1>(x)); x = fmaxf(x, lane_xor<2>(x));
    x = fmaxf(x, lane_xor<4>(x)); x = fmaxf(x, lane_xor<8>(x));
    return x;
}
__device__ __forceinline__ float rsum16(float x) {
    x += lane_xor<1>(x); x += lane_xor<2>(x);
    x += lane_xor<4>(x); x += lane_xor<8>(x);
    return x;
}

// ---------------------------------------------------------------------------
// 1. Recover source indices (order-free), layout srcs[t][n][16].
// ---------------------------------------------------------------------------
__global__ __launch_bounds__(1024) void k_srcs(const int* __restrict__ edge,
                                               int* __restrict__ srcs)
{
    __shared__ int cnt[128];
    const int t    = blockIdx.x >> 3;
    const int tgt0 = (blockIdx.x & 7) << 7;
    const int x = threadIdx.x & 31;
    const int y = threadIdx.x >> 5;
    if (threadIdx.x < 128) cnt[threadIdx.x] = 0;
    __syncthreads();

    const int c0 = 4 * x;
    const int s0 = y * 32;
    const int* e = edge + (size_t)t * Nn * Nn + tgt0 + c0;

    for (int i0 = 0; i0 < 32; i0 += 8) {
        int4 v[8];
#pragma unroll
        for (int j = 0; j < 8; ++j)
            v[j] = *reinterpret_cast<const int4*>(e + (size_t)(s0 + i0 + j) * Nn);
#pragma unroll
        for (int j = 0; j < 8; ++j) {
            const int s = s0 + i0 + j;
            if (v[j].x) { int sl = atomicAdd(&cnt[c0],     1); if (sl < KN - 1) srcs[((size_t)t * Nn + tgt0 + c0)     * KN + sl] = s; }
            if (v[j].y) { int sl = atomicAdd(&cnt[c0 + 1], 1); if (sl < KN - 1) srcs[((size_t)t * Nn + tgt0 + c0 + 1) * KN + sl] = s; }
            if (v[j].z) { int sl = atomicAdd(&cnt[c0 + 2], 1); if (sl < KN - 1) srcs[((size_t)t * Nn + tgt0 + c0 + 2) * KN + sl] = s; }
            if (v[j].w) { int sl = atomicAdd(&cnt[c0 + 3], 1); if (sl < KN - 1) srcs[((size_t)t * Nn + tgt0 + c0 + 3) * KN + sl] = s; }
        }
    }
    if (threadIdx.x < 128)
        srcs[((size_t)t * Nn + tgt0 + threadIdx.x) * KN + (KN - 1)] = tgt0 + threadIdx.x;
}

// ---------------------------------------------------------------------------
// 2. Register-blocked dual linear, HEAD-INTERLEAVED float2 output (c, c+HC).
// ---------------------------------------------------------------------------
template <int FI, int FO>
__global__ __launch_bounds__(256) void k_lin2t(
    const float* __restrict__ X,
    const float* __restrict__ Wl, const float* __restrict__ bl,
    const float* __restrict__ Wr, const float* __restrict__ br,
    float* __restrict__ Yl, float* __restrict__ Yr, int rows)
{
    constexpr int HC = FO / 2;
    constexpr int RG = 256 / HC;
    constexpr int R  = 8;
    constexpr int BR = RG * R;
    constexpr int F4 = FI / 4;
    __shared__ float xs[BR][FI];

    const int tid  = threadIdx.x;
    const int c    = tid % HC;
    const int g    = tid / HC;
    const int row0 = blockIdx.x * BR;

#pragma unroll
    for (int idx = tid; idx < BR * F4; idx += 256) {
        int r = idx / F4, q = idx % F4;
        reinterpret_cast<float4*>(&xs[r][0])[q] =
            reinterpret_cast<const float4*>(X + (size_t)(row0 + r) * FI)[q];
    }
    __syncthreads();

    float al0[R], al1[R], ar0[R], ar1[R];
    const float bl0 = bl[c], bl1 = bl[c + HC], br0 = br[c], br1 = br[c + HC];
#pragma unroll
    for (int r = 0; r < R; ++r) { al0[r] = bl0; al1[r] = bl1; ar0[r] = br0; ar1[r] = br1; }

    const int rb = g * R;
#pragma unroll
    for (int i0 = 0; i0 < FI; i0 += 4) {
        float4 xv[R];
#pragma unroll
        for (int r = 0; r < R; ++r)
            xv[r] = *reinterpret_cast<const float4*>(&xs[rb + r][i0]);
#pragma unroll
        for (int j = 0; j < 4; ++j) {
            const float wl0 = Wl[(i0 + j) * FO + c];
            const float wl1 = Wl[(i0 + j) * FO + c + HC];
            const float wr0 = Wr[(i0 + j) * FO + c];
            const float wr1 = Wr[(i0 + j) * FO + c + HC];
#pragma unroll
            for (int r = 0; r < R; ++r) {
                const float xx = (&xv[r].x)[j];
                al0[r] = fmaf(xx, wl0, al0[r]);
                al1[r] = fmaf(xx, wl1, al1[r]);
                ar0[r] = fmaf(xx, wr0, ar0[r]);
                ar1[r] = fmaf(xx, wr1, ar1[r]);
            }
        }
    }
#pragma unroll
    for (int r = 0; r < R; ++r) {
        const size_t ro = (size_t)(row0 + rb + r) * FO;
        reinterpret_cast<float2*>(Yl + ro)[c] = make_float2(al0[r], al1[r]);
        reinterpret_cast<float2*>(Yr + ro)[c] = make_float2(ar0[r], ar1[r]);
    }
}

// ---------------------------------------------------------------------------
// 2m. Merged r1+f1 projection (one launch, pointer select).
// ---------------------------------------------------------------------------
__global__ __launch_bounds__(256) void k_lin2td(
    const float* __restrict__ E,
    const float* __restrict__ WlA, const float* __restrict__ blA,
    const float* __restrict__ WrA, const float* __restrict__ brA,
    float* __restrict__ YlA, float* __restrict__ YrA,
    const float* __restrict__ WlB, const float* __restrict__ blB,
    const float* __restrict__ WrB, const float* __restrict__ brB,
    float* __restrict__ YlB, float* __restrict__ YrB)
{
    constexpr int FI = 32, FO = 128, HC = 64, R = 8, BR = 32, F4 = FI / 4;
    __shared__ float xs[BR][FI];

    int bid = blockIdx.x;
    const bool second = bid >= 992;
    if (second) bid -= 992;

    const float* X  = second ? E   : (E + (size_t)Nn * FI);
    const float* Wl = second ? WlB : WlA;
    const float* bl = second ? blB : blA;
    const float* Wr = second ? WrB : WrA;
    const float* br = second ? brB : brA;
    float* Yl = second ? YlB : YlA;
    float* Yr = second ? YrB : YrA;

    const int tid  = threadIdx.x;
    const int c    = tid % HC;
    const int g    = tid / HC;
    const int row0 = bid * BR;

#pragma unroll
    for (int idx = tid; idx < BR * F4; idx += 256) {
        int r = idx / F4, q = idx % F4;
        reinterpret_cast<float4*>(&xs[r][0])[q] =
            reinterpret_cast<const float4*>(X + (size_t)(row0 + r) * FI)[q];
    }
    __syncthreads();

    float al0[R], al1[R], ar0[R], ar1[R];
    const float bl0 = bl[c], bl1 = bl[c + HC], br0 = br[c], br1 = br[c + HC];
#pragma unroll
    for (int r = 0; r < R; ++r) { al0[r] = bl0; al1[r] = bl1; ar0[r] = br0; ar1[r] = br1; }

    const int rb = g * R;
#pragma unroll
    for (int i0 = 0; i0 < FI; i0 += 4) {
        float4 xv[R];
#pragma unroll
        for (int r = 0; r < R; ++r)
            xv[r] = *reinterpret_cast<const float4*>(&xs[rb + r][i0]);
#pragma unroll
        for (int j = 0; j < 4; ++j) {
            const float wl0 = Wl[(i0 + j) * FO + c];
            const float wl1 = Wl[(i0 + j) * FO + c + HC];
            const float wr0 = Wr[(i0 + j) * FO + c];
            const float wr1 = Wr[(i0 + j) * FO + c + HC];
#pragma unroll
            for (int r = 0; r < R; ++r) {
                const float xx = (&xv[r].x)[j];
                al0[r] = fmaf(xx, wl0, al0[r]);
                al1[r] = fmaf(xx, wl1, al1[r]);
                ar0[r] = fmaf(xx, wr0, ar0[r]);
                ar1[r] = fmaf(xx, wr1, ar1[r]);
            }
        }
    }
#pragma unroll
    for (int r = 0; r < R; ++r) {
        const size_t ro = (size_t)(row0 + rb + r) * FO;
        reinterpret_cast<float2*>(Yl + ro)[c] = make_float2(al0[r], al1[r]);
        reinterpret_cast<float2*>(Yr + ro)[c] = make_float2(ar0[r], ar1[r]);
    }
}

// ---------------------------------------------------------------------------
// 2b. Single linear to 96 cols (GRU input gates): Y = X@W^T + b.
// ---------------------------------------------------------------------------
__global__ __launch_bounds__(192) void k_lin96(
    const float* __restrict__ X, const float* __restrict__ W,
    const float* __restrict__ b, float* __restrict__ Y)
{
    __shared__ float wT[32 * 97];
    __shared__ float xs[16][32];

    const int tid = threadIdx.y * 96 + threadIdx.x;
    const int row0 = blockIdx.x * 16;

    for (int idx = tid; idx < 3072; idx += 192) {
        int c = idx >> 5, i = idx & 31;
        wT[i * 97 + c] = W[idx];
    }
    for (int idx = tid; idx < 128; idx += 192)
        reinterpret_cast<float4*>(xs)[idx] =
            reinterpret_cast<const float4*>(X + (size_t)row0 * 32)[idx];
    __syncthreads();

    const int c  = threadIdx.x;
    const int rb = threadIdx.y * 8;
    float acc[8];
    const float bc = b[c];
#pragma unroll
    for (int r = 0; r < 8; ++r) acc[r] = bc;

#pragma unroll
    for (int i = 0; i < 32; ++i) {
        const float w = wT[i * 97 + c];
#pragma unroll
        for (int r = 0; r < 8; ++r)
            acc[r] = fmaf(xs[rb + r][i], w, acc[r]);
    }
#pragma unroll
    for (int r = 0; r < 8; ++r)
        Y[(size_t)(row0 + rb + r) * 96 + c] = acc[r];
}

// ---------------------------------------------------------------------------
// 2c. Serial GRU layer: register weights, shfl broadcast, next-t gi prefetch.
// ---------------------------------------------------------------------------
__global__ __launch_bounds__(64) void k_gru1(
    const float* __restrict__ gi, const float* __restrict__ Whh,
    const float* __restrict__ bhh, float* __restrict__ E)
{
    const int d    = threadIdx.x & 31;
    const int node = blockIdx.x * 2 + (threadIdx.x >> 5);

    float wr_[32], wz_[32], wn_[32];
#pragma unroll
    for (int q = 0; q < 8; ++q) {
        *reinterpret_cast<float4*>(&wr_[q * 4]) =
            reinterpret_cast<const float4*>(Whh + (size_t)d * 32)[q];
        *reinterpret_cast<float4*>(&wz_[q * 4]) =
            reinterpret_cast<const float4*>(Whh + (size_t)(32 + d) * 32)[q];
        *reinterpret_cast<float4*>(&wn_[q * 4]) =
            reinterpret_cast<const float4*>(Whh + (size_t)(64 + d) * 32)[q];
    }
    const float br_ = bhh[d], bz_ = bhh[32 + d], bn_ = bhh[64 + d];

    size_t base = (size_t)node * 96 + d;
    float gr = gi[base], gz = gi[base + 32], gn = gi[base + 64];

    float h = 0.0f;
    for (int t = 0; t < Tt; ++t) {
        float grn = 0.f, gzn = 0.f, gnn = 0.f;
        if (t < Tt - 1) {
            const size_t nb = ((size_t)(t + 1) * Nn + node) * 96 + d;
            grn = gi[nb]; gzn = gi[nb + 32]; gnn = gi[nb + 64];
        }
        float ar = br_, az = bz_, an = bn_;
#pragma unroll
        for (int i = 0; i < 32; ++i) {
            const float hv = __shfl(h, i, 32);
            ar = fmaf(wr_[i], hv, ar);
            az = fmaf(wz_[i], hv, az);
            an = fmaf(wn_[i], hv, an);
        }
        const float r = __builtin_amdgcn_rcpf(1.0f + expf(-(gr + ar)));
        const float z = __builtin_amdgcn_rcpf(1.0f + expf(-(gz + az)));
        const float nn2 = tanhf(gn + r * an);
        h = (1.0f - z) * nn2 + z * h;
        E[((size_t)t * Nn + node) * 32 + d] = h;
        gr = grn; gz = gzn; gn = gnn;
    }
}

// ---------------------------------------------------------------------------
// Shared GATv2 C=64 wave body: 32-bit voffset gather (SGPR t-slice base),
// DPP fold, readlane alpha broadcast. Returns ELU'd result.
// ---------------------------------------------------------------------------
__device__ __forceinline__ float gat64_body(
    const float* __restrict__ gl, const float* __restrict__ gr,
    const int* __restrict__ srcs, const float* __restrict__ att,
    const float* __restrict__ bias, int wave, int lane)
{
    const int t = wave >> 10;
    const int n = wave & (Nn - 1);

    const float2 grl = reinterpret_cast<const float2*>(gr + (size_t)wave * 128)[lane];
    const float a0 = att[lane], a1 = att[64 + lane];

    const int4* sp = reinterpret_cast<const int4*>(srcs + ((size_t)t * Nn + n) * KN);
    const int4 sA = sp[0], sB = sp[1], sC = sp[2], sD = sp[3];
    int s[KN] = {sA.x, sA.y, sA.z, sA.w, sB.x, sB.y, sB.z, sB.w,
                 sC.x, sC.y, sC.z, sC.w, sD.x, sD.y, sD.z, sD.w};

    // wave-uniform t-slice base; per-k 32-bit voffset (row = 64 float2)
    const float2* glt = reinterpret_cast<const float2*>(gl) + ((size_t)t * Nn * 64);

    float2 g[KN];
    float p0[KN], p1[KN];
#pragma unroll
    for (int k = 0; k < KN; ++k) {
        g[k] = glt[(unsigned)((s[k] << 6) | lane)];
        float e0 = g[k].x + grl.x; e0 = fmaxf(e0, 0.2f * e0);
        float e1 = g[k].y + grl.y; e1 = fmaxf(e1, 0.2f * e1);
        p0[k] = e0 * a0; p1[k] = e1 * a1;
    }
    float lo0 = fold16(p0, lane);
    lo0 += lane_xor<16>(lo0); lo0 += __shfl_xor(lo0, 32);
    float lo1 = fold16(p1, lane);
    lo1 += lane_xor<16>(lo1); lo1 += __shfl_xor(lo1, 32);

    const float m0 = rmax16(lo0), m1 = rmax16(lo1);
    const float e0 = expf(lo0 - m0), e1 = expf(lo1 - m1);
    const float A0 = e0 * __builtin_amdgcn_rcpf(rsum16(e0));
    const float A1 = e1 * __builtin_amdgcn_rcpf(rsum16(e1));

    float acc0 = 0.0f, acc1 = 0.0f;
#pragma unroll
    for (int k = 0; k < KN; ++k) {
        acc0 = fmaf(bcastlane(A0, rev4(k)), g[k].x, acc0);
        acc1 = fmaf(bcastlane(A1, rev4(k)), g[k].y, acc1);
    }
    float res = 0.5f * (acc0 + acc1) + bias[lane];
    return res > 0.0f ? res : expm1f(res);
}

// ---------------------------------------------------------------------------
// 3. GATv2 C=64, plain output (g1). launch_bounds(256,4): VGPR cap 128 so
//    g[]/p[] stay in arch VGPRs (no AGPR shuttle / rematerialization).
// ---------------------------------------------------------------------------
__global__ __launch_bounds__(256, 4) void k_gat64(
    const float* __restrict__ gl, const float* __restrict__ gr,
    const int* __restrict__ srcs, const float* __restrict__ att,
    const float* __restrict__ bias, float* __restrict__ out, int rows)
{
    const int lane = threadIdx.x & 63;
    const int w = threadIdx.x >> 6;
    const int gridB = rows >> 2;
    const int chunk = gridB >> 3;
    const int bid = blockIdx.x;
    const int lb = (bid & 7) * chunk + (bid >> 3);
    const int wave = lb * 4 + w;
    const float res = gat64_body(gl, gr, srcs, att, bias, wave, lane);
    out[(size_t)wave * 64 + lane] = res;
}

// ---------------------------------------------------------------------------
// 3h. Merged dual GAT+MLP-head (same-wave LDS, no explicit waits).
// ---------------------------------------------------------------------------
__global__ __launch_bounds__(256, 4) void k_gat64h2(
    const float* __restrict__ glA, const float* __restrict__ grA,
    const int* __restrict__ srcsA, const float* __restrict__ attA,
    const float* __restrict__ biasA, float* __restrict__ outA,
    const float* __restrict__ W3A, const float* __restrict__ b3A,
    const float* __restrict__ glB, const float* __restrict__ grB,
    const int* __restrict__ srcsB, const float* __restrict__ attB,
    const float* __restrict__ biasB, float* __restrict__ outB,
    const float* __restrict__ W3B, const float* __restrict__ b3B,
    const float* __restrict__ W2, const float* __restrict__ b2)
{
    __shared__ float hb[4][64];
    constexpr int rows = (Tt - 1) * Nn;      // 31744
    constexpr int gridH = rows >> 2;          // 7936
    constexpr int chunk = gridH >> 3;         // 992

    int bid = blockIdx.x;
    const bool second = bid >= gridH;
    if (second) bid -= gridH;

    const float* gl   = second ? glB   : glA;
    const float* gr   = second ? grB   : grA;
    const int*   srcs = second ? srcsB : srcsA;
    const float* att  = second ? attB  : attA;
    const float* bias = second ? biasB : biasA;
    float*       out  = second ? outB  : outA;
    const float* W3   = second ? W3B   : W3A;
    const float* b3   = second ? b3B   : b3A;

    const int lane = threadIdx.x & 63;
    const int w = threadIdx.x >> 6;
    const int lb = (bid & 7) * chunk + (bid >> 3);
    const int wave = lb * 4 + w;

    const float res = gat64_body(gl, gr, srcs, att, bias, wave, lane);

    // tanh(res @ W2 + b2) @ W3 + b3 -> out[wave][50]   (same-wave LDS only)
    hb[w][lane] = res;
    float acc = b2[lane];
#pragma unroll
    for (int i4 = 0; i4 < 16; ++i4) {
        const float4 hv = reinterpret_cast<const float4*>(&hb[w][0])[i4];
        acc = fmaf(hv.x, W2[(i4 * 4 + 0) * 64 + lane], acc);
        acc = fmaf(hv.y, W2[(i4 * 4 + 1) * 64 + lane], acc);
        acc = fmaf(hv.z, W2[(i4 * 4 + 2) * 64 + lane], acc);
        acc = fmaf(hv.w, W2[(i4 * 4 + 3) * 64 + lane], acc);
    }
    const float th = tanhf(acc);
    hb[w][lane] = th;
    if (lane < 50) {
        float a = b3[lane];
#pragma unroll
        for (int j4 = 0; j4 < 16; ++j4) {
            const float4 hv = reinterpret_cast<const float4*>(&hb[w][0])[j4];
            a = fmaf(hv.x, W3[(j4 * 4 + 0) * 50 + lane], a);
            a = fmaf(hv.y, W3[(j4 * 4 + 1) * 50 + lane], a);
            a = fmaf(hv.z, W3[(j4 * 4 + 2) * 50 + lane], a);
            a = fmaf(hv.w, W3[(j4 * 4 + 3) * 50 + lane], a);
        }
        out[(size_t)wave * 50 + lane] = a;
    }
}

// ---------------------------------------------------------------------------
// 3b. GATv2 C=32: two targets per wave, fold within halves.
// ---------------------------------------------------------------------------
__global__ __launch_bounds__(256, 4) void k_gat32(
    const float* __restrict__ gl, const float* __restrict__ gr,
    const int* __restrict__ srcs, const float* __restrict__ att,
    const float* __restrict__ bias, float* __restrict__ out, int waves)
{
    const int lane = threadIdx.x & 63;
    const int w = threadIdx.x >> 6;
    const int gridB = waves >> 2;
    const int chunk = gridB >> 3;
    const int bid = blockIdx.x;
    const int lb = (bid & 7) * chunk + (bid >> 3);
    const int wv = lb * 4 + w;
    const int tgt = 2 * wv + (lane >> 5);
    const int t = tgt >> 10;
    const int n = tgt & (Nn - 1);
    const int c = lane & 31;

    const float2 grl = reinterpret_cast<const float2*>(gr + (size_t)tgt * 64)[c];
    const float a0 = att[c], a1 = att[32 + c];

    const int4* sp = reinterpret_cast<const int4*>(srcs + ((size_t)t * Nn + n) * KN);
    const int4 sA = sp[0], sB = sp[1], sC = sp[2], sD = sp[3];
    int s[KN] = {sA.x, sA.y, sA.z, sA.w, sB.x, sB.y, sB.z, sB.w,
                 sC.x, sC.y, sC.z, sC.w, sD.x, sD.y, sD.z, sD.w};

    // wave-uniform t-slice base; per-k 32-bit voffset (row = 32 float2)
    const float2* glt = reinterpret_cast<const float2*>(gl) + ((size_t)t * Nn * 32);

    float2 g[KN];
    float p0[KN], p1[KN];
#pragma unroll
    for (int k = 0; k < KN; ++k) {
        g[k] = glt[(unsigned)((s[k] << 5) | c)];
        float e0 = g[k].x + grl.x; e0 = fmaxf(e0, 0.2f * e0);
        float e1 = g[k].y + grl.y; e1 = fmaxf(e1, 0.2f * e1);
        p0[k] = e0 * a0; p1[k] = e1 * a1;
    }
    float lo0 = fold16(p0, lane); lo0 += lane_xor<16>(lo0);
    float lo1 = fold16(p1, lane); lo1 += lane_xor<16>(lo1);

    const float m0 = rmax16(lo0), m1 = rmax16(lo1);
    const float e0 = expf(lo0 - m0), e1 = expf(lo1 - m1);
    const float A0 = e0 * __builtin_amdgcn_rcpf(rsum16(e0));
    const float A1 = e1 * __builtin_amdgcn_rcpf(rsum16(e1));

    const float A0o = __shfl_xor(A0, 32);
    const float A1o = __shfl_xor(A1, 32);
    const bool loHalf = (lane < 32);

    float acc0 = 0.0f, acc1 = 0.0f;
#pragma unroll
    for (int k = 0; k < KN; ++k) {
        const float b0a = bcastlane(A0, rev4(k)), b0b = bcastlane(A0o, rev4(k));
        const float b1a = bcastlane(A1, rev4(k)), b1b = bcastlane(A1o, rev4(k));
        acc0 = fmaf(loHalf ? b0a : b0b, g[k].x, acc0);
        acc1 = fmaf(loHalf ? b1a : b1b, g[k].y, acc1);
    }
    float res = 0.5f * (acc0 + acc1) + bias[c];
    res = res > 0.0f ? res : expm1f(res);
    out[(size_t)tgt * 32 + c] = res;
}

// ---------------------------------------------------------------------------
extern "C" void kernel_launch(void* const* d_in, const int* in_sizes, int n_in,
                              void* d_out, int out_size, void* d_ws, size_t ws_size,
                              hipStream_t stream)
{
    const float* x    = (const float*)d_in[0];
    const int*   edge = (const int*)d_in[1];

    const float *g1_Wl = (const float*)d_in[2],  *g1_bl = (const float*)d_in[3];
    const float *g1_Wr = (const float*)d_in[4],  *g1_br = (const float*)d_in[5];
    const float *g1_att= (const float*)d_in[6],  *g1_b  = (const float*)d_in[7];
    const float *g2_Wl = (const float*)d_in[8],  *g2_bl = (const float*)d_in[9];
    const float *g2_Wr = (const float*)d_in[10], *g2_br = (const float*)d_in[11];
    const float *g2_att= (const float*)d_in[12], *g2_b  = (const float*)d_in[13];
    const float *r1_Wl = (const float*)d_in[14], *r1_bl = (const float*)d_in[15];
    const float *r1_Wr = (const float*)d_in[16], *r1_br = (const float*)d_in[17];
    const float *r1_att= (const float*)d_in[18], *r1_b  = (const float*)d_in[19];
    const float *f1_Wl = (const float*)d_in[20], *f1_bl = (const float*)d_in[21];
    const float *f1_Wr = (const float*)d_in[22], *f1_br = (const float*)d_in[23];
    const float *f1_att= (const float*)d_in[24], *f1_b  = (const float*)d_in[25];
    const float *gru0_Wih = (const float*)d_in[26], *gru0_Whh = (const float*)d_in[27];
    const float *gru0_bih = (const float*)d_in[28], *gru0_bhh = (const float*)d_in[29];
    const float *gru1_Wih = (const float*)d_in[30], *gru1_Whh = (const float*)d_in[31];
    const float *gru1_bih = (const float*)d_in[32], *gru1_bhh = (const float*)d_in[33];
    const float *rec2_W = (const float*)d_in[34], *rec2_b = (const float*)d_in[35];
    const float *rec3_W = (const float*)d_in[36], *rec3_b = (const float*)d_in[37];
    const float *fore3_W= (const float*)d_in[38], *fore3_b= (const float*)d_in[39];

    // workspace layout
    char* ws = (char*)d_ws;
    int*   srcs = (int*)ws;                              // [32][1024][16] (2 MB)
    float* buf1 = (float*)(ws + (4u << 20));             // [32768,128] 16 MB
    float* buf2 = buf1 + (size_t)32768 * 128;            // [32768,128] 16 MB
    float* buf3 = buf2 + (size_t)32768 * 128;            // [32768,128] 16 MB
    float* buf4 = buf3 + (size_t)32768 * 128;            // [32768,128] 16 MB
    float* buf5 = buf4 + (size_t)32768 * 128;            // [32768,64]   8 MB
    float* buf6 = buf5 + (size_t)32768 * 64;             // [32768,32]   4 MB

    float* recon = (float*)d_out;                        // [31,1024,50]
    float* fore  = recon + (size_t)31 * 1024 * 50;       // [31,1024,50]
    float* E     = fore  + (size_t)31 * 1024 * 50;       // [32,1024,32]

    // 1. adjacency -> source lists
    k_srcs<<<Tt * 8, 1024, 0, stream>>>(edge, srcs);

    // 2. GAT g1 (64 -> 64)
    k_lin2t<64, 128><<<1024, 256, 0, stream>>>(x, g1_Wl, g1_bl, g1_Wr, g1_br, buf1, buf2, 32768);
    k_gat64<<<8192, 256, 0, stream>>>(buf1, buf2, srcs, g1_att, g1_b, buf5, 32768);

    // 3. GAT g2 (64 -> 32)
    k_lin2t<64, 64><<<512, 256, 0, stream>>>(buf5, g2_Wl, g2_bl, g2_Wr, g2_br, buf1, buf2, 32768);
    k_gat32<<<4096, 256, 0, stream>>>(buf1, buf2, srcs, g2_att, g2_b, buf6, 16384);

    // 4. GRU stack: input gates (parallel GEMM) + serial layer, twice
    k_lin96<<<2048, dim3(96, 2), 0, stream>>>(buf6, gru0_Wih, gru0_bih, buf1);   // GI0
    k_gru1<<<512, 64, 0, stream>>>(buf1, gru0_Whh, gru0_bhh, buf5);              // E0
    k_lin96<<<2048, dim3(96, 2), 0, stream>>>(buf5, gru1_Wih, gru1_bih, buf2);   // GI1
    k_gru1<<<512, 64, 0, stream>>>(buf2, gru1_Whh, gru1_bhh, E);                 // E

    // 5. r1+f1 projections in one launch (pointer select)
    k_lin2td<<<1984, 256, 0, stream>>>(E,
        r1_Wl, r1_bl, r1_Wr, r1_br, buf1, buf2,
        f1_Wl, f1_bl, f1_Wr, f1_br, buf3, buf4);

    // 6. merged dual GAT+head: reconstruct + forecast in ONE launch
    k_gat64h2<<<15872, 256, 0, stream>>>(
        buf1, buf2, srcs + (size_t)KN * Nn, r1_att, r1_b, recon, rec3_W, rec3_b,
        buf3, buf4, srcs,                   f1_att, f1_b, fore,  fore3_W, fore3_b,
        rec2_W, rec2_b);

    (void)in_sizes; (void)n_in; (void)out_size; (void)ws_size;
}